// Round 23
// baseline (94.903 us; speedup 1.0000x reference)
//
#include <hip/hip_runtime.h>

#define Bb 8
#define Tt 512
#define Uu 128
#define U1 129
#define Vv 128

#define OUT_OFF 0                          // float2 OUT[b][t][u] linear
#define CTROWS 321                         // pair rows m = 0..320 (1..320 used)
#define PCKROW 512                         // floats per packed pair row (64 lanes x 8)
#define PCKBSZ ((size_t)CTROWS * PCKROW)
#define PCK_OFF ((size_t)Bb * Tt * U1 * 2)
#define CTCOL_OFF (PCK_OFF + (size_t)Bb * PCKBSZ)      // float4 {A,B,C,0}[b][m] (u=128)
// k=4 condensed tables: W row q covers diags 4q-4 -> 4q
#define WROWF 768                          // 64 lanes x 12 floats (10 used)
#define WROWS 160                          // q = 0..159 (1..159 used)
#define WBSZ ((size_t)WROWS * WROWF)
#define W_OFF (CTCOL_OFF + (size_t)Bb * CTROWS * 4)
#define WCOL_OFF (W_OFF + (size_t)Bb * WBSZ)           // 8 floats per (b,q): u=128 coeffs
#define RES_OFF (WCOL_OFF + (size_t)Bb * WROWS * 8)

#define K_LN2    0.6931471805599453f
#define K_INVLN2 1.4426950408889634f
#define SENT (-1.0e30f)                    // finite sentinel; exp2(-big)=0, no inf/NaN

__device__ __forceinline__ float fexp2(float x) {
    float r; asm("v_exp_f32 %0, %1" : "=v"(r) : "v"(x)); return r;
}
__device__ __forceinline__ float flog2(float x) {
    float r; asm("v_log_f32 %0, %1" : "=v"(r) : "v"(x)); return r;
}
__device__ __forceinline__ float fmax3(float x, float y, float z) {
    float r; asm("v_max3_f32 %0, %1, %2, %3" : "=v"(r) : "v"(x), "v"(y), "v"(z));
    return r;
}

// Stage A: band-restricted streaming LSE (r15 structure, unchanged).
__global__ __launch_bounds__(256) void lse_kernel(
    const float* __restrict__ logits, const int* __restrict__ y,
    const int* __restrict__ logit_lens, const int* __restrict__ y_lens,
    float* __restrict__ ws)
{
    const int b = blockIdx.y;
    const int t = blockIdx.x;
    if (t >= logit_lens[b]) return;
    const int Ue = y_lens[b];

    float2* outv = (float2*)(ws + OUT_OFF);
    const int wid  = threadIdx.x >> 6;
    const int lane = threadIdx.x & 63;
    const int g    = lane >> 4;
    const int gl   = lane & 15;
    const unsigned rowbase = ((unsigned)b * Tt + t) * U1;
    const int yb = b * Uu;

    for (int u0 = wid * 8; u0 <= Ue; u0 += 32) {
        const int ua = u0 + g;
        const int ub = u0 + 4 + g;
        const int uca = ua > Ue ? Ue : ua;
        const int ucb = ub > Ue ? Ue : ub;
        const float* pa = logits + (size_t)(rowbase + uca) * Vv;
        const float* pb = logits + (size_t)(rowbase + ucb) * Vv;
        float4 a1 = *(const float4*)(pa + gl * 4);
        float4 a2 = *(const float4*)(pa + 64 + gl * 4);
        float4 b1 = *(const float4*)(pb + gl * 4);
        float4 b2 = *(const float4*)(pb + 64 + gl * 4);

        float sa = (fexp2(a1.x * K_INVLN2) + fexp2(a1.y * K_INVLN2))
                 + (fexp2(a1.z * K_INVLN2) + fexp2(a1.w * K_INVLN2))
                 + (fexp2(a2.x * K_INVLN2) + fexp2(a2.y * K_INVLN2))
                 + (fexp2(a2.z * K_INVLN2) + fexp2(a2.w * K_INVLN2));
        float sb = (fexp2(b1.x * K_INVLN2) + fexp2(b1.y * K_INVLN2))
                 + (fexp2(b1.z * K_INVLN2) + fexp2(b1.w * K_INVLN2))
                 + (fexp2(b2.x * K_INVLN2) + fexp2(b2.y * K_INVLN2))
                 + (fexp2(b2.z * K_INVLN2) + fexp2(b2.w * K_INVLN2));
        #pragma unroll
        for (int off = 8; off; off >>= 1) {
            sa += __shfl_xor(sa, off);
            sb += __shfl_xor(sb, off);
        }
        float lseA = flog2(sa);
        float lseB = flog2(sb);

        float emA = SENT, emB = SENT;
        if (uca < Uu) {
            int yv = y[yb + uca];
            int c = yv & 3;
            float4 cv = (yv & 64) ? a2 : a1;
            float cand = (c == 0) ? cv.x : (c == 1) ? cv.y : (c == 2) ? cv.z : cv.w;
            float ev = __shfl(cand, (lane & 48) | ((yv & 63) >> 2));
            emA = ev * K_INVLN2 - lseA;
        }
        if (ucb < Uu) {
            int yv = y[yb + ucb];
            int c = yv & 3;
            float4 cv = (yv & 64) ? b2 : b1;
            float cand = (c == 0) ? cv.x : (c == 1) ? cv.y : (c == 2) ? cv.z : cv.w;
            float ev = __shfl(cand, (lane & 48) | ((yv & 63) >> 2));
            emB = ev * K_INVLN2 - lseB;
        }
        if (gl == 0) {
            if (ua <= Ue) outv[rowbase + ua] = make_float2(a1.x * K_INVLN2 - lseA, emA);
            if (ub <= Ue) outv[rowbase + ub] = make_float2(b1.x * K_INVLN2 - lseB, emB);
        }
    }
}

__device__ __forceinline__ float lae2(float x, float y) {
    float dd = x - y;
    float nad = __builtin_bit_cast(float, __builtin_bit_cast(int, dd) | 0x80000000);
    return fmaxf(x, y) + flog2(1.0f + fexp2(nad));
}
__device__ __forceinline__ float lae3(float x, float y, float z) {
    float m = fmax3(x, y, z);
    return m + flog2(fexp2(x - m) + fexp2(y - m) + fexp2(z - m));
}
__device__ __forceinline__ float lae5(float a, float b, float c, float d, float e) {
    float m = fmax3(a, b, c);
    m = fmax3(m, d, e);
    return m + flog2(fexp2(a - m) + fexp2(b - m) + fexp2(c - m)
                   + fexp2(d - m) + fexp2(e - m));
}

// Stage B: pair-condensation coefficients, PACKED (r15 structure, unchanged).
__global__ __launch_bounds__(256) void cond_kernel(
    const int* __restrict__ logit_lens, const int* __restrict__ y_lens,
    float* __restrict__ ws)
{
    const int b = blockIdx.x / 320;
    const int m = blockIdx.x - b * 320 + 1;
    if (m > ((logit_lens[b] - 1 + y_lens[b]) >> 1)) return;
    const int r1 = 2 * m - 2, r2 = 2 * m - 1;
    const float2* outv = (const float2*)(ws + OUT_OFF);

    __shared__ float2 D1[U1], D2[U1];
    __shared__ float pckS[PCKROW];
    for (int q = threadIdx.x; q < 2 * U1; q += 256) {
        const int which = q >= U1;
        const int j = q - which * U1;
        const int t = (which ? r2 : r1) - j;
        float2 val = make_float2(SENT, SENT);
        if (t >= 0 && t < Tt) val = outv[((size_t)b * Tt + t) * U1 + j];
        (which ? D2 : D1)[j] = val;
    }
    __syncthreads();

    const int u = threadIdx.x;
    if (u <= 128) {
        float2 d1  = D1[u], d2 = D2[u];
        float2 d1m = (u >= 1) ? D1[u - 1] : make_float2(SENT, SENT);
        float d2my  = (u >= 1) ? D2[u - 1].y : SENT;
        float d1m2y = (u >= 2) ? D1[u - 2].y : SENT;
        float A = d1.x + d2.x;
        float B = lae2(d1m.y + d2.x, d1m.x + d2my);
        float C = d1m2y + d2my;
        if (u < 128) {
            int base = (u >> 1) * 8 + (u & 1);
            pckS[base]     = A;
            pckS[base + 2] = B;
            pckS[base + 4] = C;
            if ((u & 1) == 0) { pckS[base + 6] = 0.0f; pckS[base + 7] = 0.0f; }
        } else {
            ((float4*)(ws + CTCOL_OFF))[(size_t)b * CTROWS + m] = make_float4(A, B, C, 0.0f);
        }
    }
    __syncthreads();

    float* pckG = ws + PCK_OFF + (size_t)b * PCKBSZ + (size_t)m * PCKROW;
    for (int i = threadIdx.x; i < PCKROW; i += 256) pckG[i] = pckS[i];
}

// Stage C: k=4 condensation (r20 structure, unchanged).
__global__ __launch_bounds__(256) void compose_kernel(
    const int* __restrict__ logit_lens, const int* __restrict__ y_lens,
    float* __restrict__ ws)
{
    const int b = blockIdx.x / 159;
    const int q = blockIdx.x - b * 159 + 1;        // 1..159
    const int dend = logit_lens[b] - 1 + y_lens[b];
    if (4 * q > dend) return;
    const int m1 = 2 * q - 1, m2 = 2 * q;
    const float* PCKb = ws + PCK_OFF + (size_t)b * PCKBSZ;
    const float4* COLb = (const float4*)(ws + CTCOL_OFF) + (size_t)b * CTROWS;

    __shared__ float a1s[131], b1s[131], c1s[131];  // index u+2, [0..1]=SENT pad
    __shared__ float wrk[WROWF];
    const int u = threadIdx.x;
    if (u < 2) { a1s[u] = SENT; b1s[u] = SENT; c1s[u] = SENT; }
    if (u < 128) {
        const float* p = PCKb + (size_t)m1 * PCKROW + (u >> 1) * 8;
        int par = u & 1;
        a1s[u + 2] = p[par]; b1s[u + 2] = p[2 + par]; c1s[u + 2] = p[4 + par];
    } else if (u == 128) {
        float4 cc = COLb[m1];
        a1s[130] = cc.x; b1s[130] = cc.y; c1s[130] = cc.z;
    }
    __syncthreads();

    if (u <= 128) {
        float A2, B2, C2;
        if (u < 128) {
            const float* p = PCKb + (size_t)m2 * PCKROW + (u >> 1) * 8;
            int par = u & 1;
            A2 = p[par]; B2 = p[2 + par]; C2 = p[4 + par];
        } else {
            float4 cc = COLb[m2];
            A2 = cc.x; B2 = cc.y; C2 = cc.z;
        }
        float A1 = a1s[u + 2], A1m = a1s[u + 1], A1m2 = a1s[u];
        float B1 = b1s[u + 2], B1m = b1s[u + 1], B1m2 = b1s[u];
        float C1 = c1s[u + 2], C1m = c1s[u + 1], C1m2 = c1s[u];
        float W0 = A2 + A1;
        float W1 = lae2(A2 + B1, B2 + A1m);
        float W2 = lae3(A2 + C1, B2 + B1m, C2 + A1m2);
        float W3 = lae2(B2 + C1m, C2 + B1m2);
        float W4 = C2 + C1m2;
        if (u < 128) {
            int base = (u >> 1) * 12 + (u & 1);
            wrk[base]     = W0;
            wrk[base + 2] = W1;
            wrk[base + 4] = W2;
            wrk[base + 6] = W3;
            wrk[base + 8] = W4;
            if ((u & 1) == 0) { wrk[base + 10] = 0.0f; wrk[base + 11] = 0.0f; }
        } else {
            float* wc = ws + WCOL_OFF + ((size_t)b * WROWS + q) * 8;
            wc[0] = W0; wc[1] = W1; wc[2] = W2; wc[3] = W3; wc[4] = W4;
            wc[5] = 0.0f; wc[6] = 0.0f; wc[7] = 0.0f;
        }
    }
    __syncthreads();

    float* wg = ws + W_OFF + (size_t)b * WBSZ + (size_t)q * WROWF;
    for (int i = threadIdx.x; i < WROWF; i += 256) wg[i] = wrk[i];
}

// rotate lane i <- lane i-1 (mod 64). MODE 0/1: DPP (runtime-verified), 2: shuffle.
template<int MODE>
__device__ __forceinline__ float rot1(float x, int lane) {
    if constexpr (MODE == 2) {
        float s = __shfl_up(x, 1);
        float w = __shfl(x, 63);
        return (lane == 0) ? w : s;
    } else {
        constexpr int CTRL = (MODE == 0) ? 0x13C : 0x134;
        int i = __builtin_bit_cast(int, x);
        i = __builtin_amdgcn_update_dpp(i, i, CTRL, 0xF, 0xF, true);
        return __builtin_bit_cast(float, i);
    }
}

// DP over k=4 condensed diagonals (r20 body, unchanged math). NEW: all 8 batch
// chains run as 8 WAVES OF ONE BLOCK (one CU, 2 waves/SIMD) so each SIMD
// interleaves two independent chains -> dependent VALU/trans latency (the
// measured ~470cy/iter single-wave bound) is ~half hidden. No barriers.
template<int MODE, bool H128>
__device__ __forceinline__ void dp_body(int b, int lane, int Tb, int Ub,
                                        float* __restrict__ ws)
{
    const float2* outv = (const float2*)(ws + OUT_OFF);
    const float* PCKb = ws + PCK_OFF + (size_t)b * PCKBSZ;
    const float4* COLb = (const float4*)(ws + CTCOL_OFF) + (size_t)b * CTROWS;
    const float* WTb = ws + W_OFF + (size_t)b * WBSZ;
    const float* WCb = ws + WCOL_OFF + (size_t)b * WROWS * 8;
    int zv; asm volatile("v_mov_b32 %0, 0" : "=v"(zv));  // opaque 0: force VMEM

    float px = (lane == 0) ? 0.0f : SENT;
    float py = SENT, p2 = SENT;
    const int dend = Tb - 1 + Ub;      // in [319, 639]
    const int nq   = dend >> 2;        // k=4 iterations (79..159)
    const int rem  = dend & 3;

    // tail loads issued up-front (retired long before use)
    const int mpair = 2 * nq + 1;
    float4 Qp = *(const float4*)(PCKb + (size_t)mpair * PCKROW + (lane << 3));
    float2 Rp = *(const float2*)(PCKb + (size_t)mpair * PCKROW + (lane << 3) + 4);
    float4 Op = make_float4(SENT, SENT, SENT, 0.0f);
    if constexpr (H128) Op = COLb[mpair + zv];

    float2 F1 = make_float2(0,0), F2 = make_float2(0,0), G = make_float2(0,0);
    if (rem & 1) {
        const int r = dend - 1;
        int j1 = 2 * lane, j2 = 2 * lane + 1;
        int t1 = r - j1; t1 = t1 > Tt - 1 ? Tt - 1 : t1;
        int t2 = r - j2; t2 = t2 > Tt - 1 ? Tt - 1 : t2;
        F1 = outv[((size_t)b * Tt + t1) * U1 + j1];
        F2 = outv[((size_t)b * Tt + t2) * U1 + j2];
        if constexpr (H128) G = outv[((size_t)b * Tt + (r - 128)) * U1 + 128];
    }
    float pbf = outv[((size_t)b * Tt + (Tb - 1)) * U1 + Ub + zv].x;

    float4 A0,A1,A2,A3,A4,A5,A6,A7;    // {W0e,W0o,W1e,W1o}
    float4 B0,B1,B2,B3,B4,B5,B6,B7;    // {W2e,W2o,W3e,W3o}
    float2 C0,C1,C2,C3,C4,C5,C6,C7;    // {W4e,W4o}
    float4 Oa0,Oa1,Oa2,Oa3,Oa4,Oa5,Oa6,Oa7;  // u=128: {W0,W1,W2,W3}
    float2 Oc0,Oc1,Oc2,Oc3,Oc4,Oc5,Oc6,Oc7;  // u=128: {W4,pad}

#define LOADW(i, qq) { unsigned o = (unsigned)(qq) * WROWF + lane * 12; \
    A##i = *(const float4*)(WTb + o); \
    B##i = *(const float4*)(WTb + o + 4); \
    C##i = *(const float2*)(WTb + o + 8); \
    if constexpr (H128) { \
        Oa##i = *(const float4*)(WCb + (qq) * 8 + zv); \
        Oc##i = *(const float2*)(WCb + (qq) * 8 + 4 + zv); } }

#define PIN(i) if constexpr (H128) { \
        asm volatile("" : "+v"(A##i.x), "+v"(A##i.y), "+v"(A##i.z), "+v"(A##i.w), \
                          "+v"(B##i.x), "+v"(B##i.y), "+v"(B##i.z), "+v"(B##i.w), \
                          "+v"(C##i.x), "+v"(C##i.y), \
                          "+v"(Oa##i.x), "+v"(Oa##i.y), "+v"(Oa##i.z), "+v"(Oa##i.w), \
                          "+v"(Oc##i.x)); \
    } else { \
        asm volatile("" : "+v"(A##i.x), "+v"(A##i.y), "+v"(A##i.z), "+v"(A##i.w), \
                          "+v"(B##i.x), "+v"(B##i.y), "+v"(B##i.z), "+v"(B##i.w), \
                          "+v"(C##i.x), "+v"(C##i.y)); \
    }

    // even u=2l: alpha[u-1..u-4] = p1y, p1x, p2y, p2x; odd u=2l+1: px, p1y, p1x, p2y
#define COMP4(i) { \
    float p1y = rot1<MODE>(py, lane); \
    float p1x = rot1<MODE>(px, lane); \
    float p2y = rot1<MODE>(p1y, lane); \
    float p2x = rot1<MODE>(p1x, lane); \
    float nx = lae5(px + A##i.x, p1y + A##i.z, p1x + B##i.x, p2y + B##i.z, p2x + C##i.x); \
    float ny = lae5(py + A##i.y, px + A##i.w, p1y + B##i.y, p1x + B##i.w, p2y + C##i.y); \
    if constexpr (H128) p2 = lae5(p2 + Oa##i.x, p1y + Oa##i.y, p1x + Oa##i.z, \
                                  p2y + Oa##i.w, p2x + Oc##i.x); \
    px = nx; py = ny; }

    LOADW(0,1) LOADW(1,2) LOADW(2,3) LOADW(3,4)
    LOADW(4,5) LOADW(5,6) LOADW(6,7) LOADW(7,8)

    int q = 1;
    for (; q + 7 <= nq; q += 8) {
        PIN(0) COMP4(0) { int dn = q + 8  > nq ? nq : q + 8;  LOADW(0, dn) }
        PIN(1) COMP4(1) { int dn = q + 9  > nq ? nq : q + 9;  LOADW(1, dn) }
        PIN(2) COMP4(2) { int dn = q + 10 > nq ? nq : q + 10; LOADW(2, dn) }
        PIN(3) COMP4(3) { int dn = q + 11 > nq ? nq : q + 11; LOADW(3, dn) }
        PIN(4) COMP4(4) { int dn = q + 12 > nq ? nq : q + 12; LOADW(4, dn) }
        PIN(5) COMP4(5) { int dn = q + 13 > nq ? nq : q + 13; LOADW(5, dn) }
        PIN(6) COMP4(6) { int dn = q + 14 > nq ? nq : q + 14; LOADW(6, dn) }
        PIN(7) COMP4(7) { int dn = q + 15 > nq ? nq : q + 15; LOADW(7, dn) }
    }
#define TAILW(i) if (q <= nq) { PIN(i) COMP4(i) q++; }
    TAILW(0) TAILW(1) TAILW(2) TAILW(3) TAILW(4) TAILW(5) TAILW(6)

    if (rem >= 2) {   // pair step: diag 4nq -> 4nq+2
        float pm1 = rot1<MODE>(py, lane);
        float pm0 = rot1<MODE>(px, lane);
        float nx = lae3(px + Qp.x, pm1 + Qp.z, pm0 + Rp.x);
        float ny = lae3(py + Qp.y, px + Qp.w, pm1 + Rp.y);
        if constexpr (H128) p2 = lae3(p2 + Op.x, pm1 + Op.y, pm0 + Op.z);
        px = nx; py = ny;
    }
    if (rem & 1) {    // single step: diag dend-1 -> dend, operands from OUT
        float pm  = rot1<MODE>(py, lane);
        float pmE = rot1<MODE>(F2.y, lane);
        float pmE0 = (lane == 0) ? SENT : pmE;
        float nx = lae2(px + F1.x, pm + pmE0);
        float ny = lae2(py + F2.x, px + F1.y);
        if constexpr (H128) p2 = lae2(p2 + G.x, pm + pmE);
        px = nx; py = ny;
    }

    float a;
    if constexpr (H128) {
        a = __shfl(p2, 0);
    } else {
        float ax = __shfl(px, Ub >> 1);
        float ay = __shfl(py, Ub >> 1);
        a = (Ub & 1) ? ay : ax;
    }
    if (lane == 0) {
        ws[RES_OFF + b] = -(a + pbf) * K_LN2;
    }
#undef LOADW
#undef PIN
#undef COMP4
#undef TAILW
}

__global__ __launch_bounds__(512) void dp_kernel(
    const int* __restrict__ logit_lens, const int* __restrict__ y_lens,
    float* __restrict__ ws)
{
    const int b = threadIdx.x >> 6;        // wave id = batch (8 waves, 1 block, 1 CU)
    const int lane = threadIdx.x & 63;
    const int Tb = logit_lens[b];
    const int Ub = y_lens[b];
    const bool h = (Ub == 128);
    int li = lane;
    int r0 = __builtin_amdgcn_update_dpp(li, li, 0x13C /*WAVE_ROR1*/, 0xF, 0xF, true);
    int r1 = __builtin_amdgcn_update_dpp(li, li, 0x134 /*WAVE_ROL1*/, 0xF, 0xF, true);
    int want = (lane + 63) & 63;
    if (__all(r0 == want)) {
        if (h) dp_body<0, true>(b, lane, Tb, Ub, ws);
        else   dp_body<0, false>(b, lane, Tb, Ub, ws);
    } else if (__all(r1 == want)) {
        if (h) dp_body<1, true>(b, lane, Tb, Ub, ws);
        else   dp_body<1, false>(b, lane, Tb, Ub, ws);
    } else {
        if (h) dp_body<2, true>(b, lane, Tb, Ub, ws);
        else   dp_body<2, false>(b, lane, Tb, Ub, ws);
    }
}

__global__ void mean_kernel(const float* __restrict__ res, float* __restrict__ out)
{
    if (threadIdx.x == 0) {
        float s = 0.0f;
        #pragma unroll
        for (int i = 0; i < Bb; ++i) s += res[i];
        out[0] = s * (1.0f / Bb);
    }
}

extern "C" void kernel_launch(void* const* d_in, const int* in_sizes, int n_in,
                              void* d_out, int out_size, void* d_ws, size_t ws_size,
                              hipStream_t stream) {
    const float* logits     = (const float*)d_in[0];
    const int*   y          = (const int*)d_in[1];
    const int*   logit_lens = (const int*)d_in[2];
    const int*   y_lens     = (const int*)d_in[3];
    float* ws  = (float*)d_ws;
    float* out = (float*)d_out;

    dim3 lgrid(Tt, Bb);
    lse_kernel<<<lgrid, 256, 0, stream>>>(logits, y, logit_lens, y_lens, ws);
    cond_kernel<<<Bb * 320, 256, 0, stream>>>(logit_lens, y_lens, ws);
    compose_kernel<<<Bb * 159, 256, 0, stream>>>(logit_lens, y_lens, ws);
    dp_kernel<<<1, 512, 0, stream>>>(logit_lens, y_lens, ws);
    mean_kernel<<<1, 64, 0, stream>>>(ws + RES_OFF, out);
}

// Round 24
// 64.545 us; speedup vs baseline: 1.4703x; 1.4703x over previous
//
#include <hip/hip_runtime.h>

#define Bb 8
#define Tt 512
#define Uu 128
#define U1 129
#define Vv 128

#define OUT_OFF 0                          // float2 OUT[b][t][u] linear
#define CTROWS 321                         // pair rows m = 0..320 (1..320 used)
#define PCKROW 512                         // floats per packed pair row (64 lanes x 8)
#define PCKBSZ ((size_t)CTROWS * PCKROW)
#define PCK_OFF ((size_t)Bb * Tt * U1 * 2)
#define CTCOL_OFF (PCK_OFF + (size_t)Bb * PCKBSZ)      // float4 {A,B,C,0}[b][m] (u=128)
#define WROWF 768                          // 64 lanes x 12 floats
#define WROWS 160                          // q = 0..159 (1..159 used)
#define WBSZ ((size_t)WROWS * WROWF)
#define W_OFF (CTCOL_OFF + (size_t)Bb * CTROWS * 4)    // forward k=4 records
#define WCOL_OFF (W_OFF + (size_t)Bb * WBSZ)           // 8 floats per (b,q): u=128 row
#define WB_OFF (WCOL_OFF + (size_t)Bb * WROWS * 8)     // BACKWARD (transposed) records
#define ST_OFF (WB_OFF + (size_t)Bb * WBSZ)            // per b: fw 130 floats, bw 130
#define RES_OFF (ST_OFF + (size_t)Bb * 260)

#define K_LN2    0.6931471805599453f
#define K_INVLN2 1.4426950408889634f
#define SENT (-1.0e30f)                    // finite sentinel; exp2(-big)=0, no inf/NaN

__device__ __forceinline__ float fexp2(float x) {
    float r; asm("v_exp_f32 %0, %1" : "=v"(r) : "v"(x)); return r;
}
__device__ __forceinline__ float flog2(float x) {
    float r; asm("v_log_f32 %0, %1" : "=v"(r) : "v"(x)); return r;
}
__device__ __forceinline__ float fmax3(float x, float y, float z) {
    float r; asm("v_max3_f32 %0, %1, %2, %3" : "=v"(r) : "v"(x), "v"(y), "v"(z));
    return r;
}
__device__ __forceinline__ float lae2(float x, float y) {
    float dd = x - y;
    float nad = __builtin_bit_cast(float, __builtin_bit_cast(int, dd) | 0x80000000);
    return fmaxf(x, y) + flog2(1.0f + fexp2(nad));
}
__device__ __forceinline__ float lae3(float x, float y, float z) {
    float m = fmax3(x, y, z);
    return m + flog2(fexp2(x - m) + fexp2(y - m) + fexp2(z - m));
}
__device__ __forceinline__ float lae5(float a, float b, float c, float d, float e) {
    float m = fmax3(a, b, c);
    m = fmax3(m, d, e);
    return m + flog2(fexp2(a - m) + fexp2(b - m) + fexp2(c - m)
                   + fexp2(d - m) + fexp2(e - m));
}
__device__ __forceinline__ float lae6(float a, float b, float c, float d, float e, float f) {
    float m = fmaxf(fmax3(a, b, c), fmax3(d, e, f));
    return m + flog2(fexp2(a - m) + fexp2(b - m) + fexp2(c - m)
                   + fexp2(d - m) + fexp2(e - m) + fexp2(f - m));
}

// Stage A: band-restricted streaming LSE (unchanged).
__global__ __launch_bounds__(256) void lse_kernel(
    const float* __restrict__ logits, const int* __restrict__ y,
    const int* __restrict__ logit_lens, const int* __restrict__ y_lens,
    float* __restrict__ ws)
{
    const int b = blockIdx.y;
    const int t = blockIdx.x;
    if (t >= logit_lens[b]) return;
    const int Ue = y_lens[b];

    float2* outv = (float2*)(ws + OUT_OFF);
    const int wid  = threadIdx.x >> 6;
    const int lane = threadIdx.x & 63;
    const int g    = lane >> 4;
    const int gl   = lane & 15;
    const unsigned rowbase = ((unsigned)b * Tt + t) * U1;
    const int yb = b * Uu;

    for (int u0 = wid * 8; u0 <= Ue; u0 += 32) {
        const int ua = u0 + g;
        const int ub = u0 + 4 + g;
        const int uca = ua > Ue ? Ue : ua;
        const int ucb = ub > Ue ? Ue : ub;
        const float* pa = logits + (size_t)(rowbase + uca) * Vv;
        const float* pb = logits + (size_t)(rowbase + ucb) * Vv;
        float4 a1 = *(const float4*)(pa + gl * 4);
        float4 a2 = *(const float4*)(pa + 64 + gl * 4);
        float4 b1 = *(const float4*)(pb + gl * 4);
        float4 b2 = *(const float4*)(pb + 64 + gl * 4);

        float sa = (fexp2(a1.x * K_INVLN2) + fexp2(a1.y * K_INVLN2))
                 + (fexp2(a1.z * K_INVLN2) + fexp2(a1.w * K_INVLN2))
                 + (fexp2(a2.x * K_INVLN2) + fexp2(a2.y * K_INVLN2))
                 + (fexp2(a2.z * K_INVLN2) + fexp2(a2.w * K_INVLN2));
        float sb = (fexp2(b1.x * K_INVLN2) + fexp2(b1.y * K_INVLN2))
                 + (fexp2(b1.z * K_INVLN2) + fexp2(b1.w * K_INVLN2))
                 + (fexp2(b2.x * K_INVLN2) + fexp2(b2.y * K_INVLN2))
                 + (fexp2(b2.z * K_INVLN2) + fexp2(b2.w * K_INVLN2));
        #pragma unroll
        for (int off = 8; off; off >>= 1) {
            sa += __shfl_xor(sa, off);
            sb += __shfl_xor(sb, off);
        }
        float lseA = flog2(sa);
        float lseB = flog2(sb);

        float emA = SENT, emB = SENT;
        if (uca < Uu) {
            int yv = y[yb + uca];
            int c = yv & 3;
            float4 cv = (yv & 64) ? a2 : a1;
            float cand = (c == 0) ? cv.x : (c == 1) ? cv.y : (c == 2) ? cv.z : cv.w;
            float ev = __shfl(cand, (lane & 48) | ((yv & 63) >> 2));
            emA = ev * K_INVLN2 - lseA;
        }
        if (ucb < Uu) {
            int yv = y[yb + ucb];
            int c = yv & 3;
            float4 cv = (yv & 64) ? b2 : b1;
            float cand = (c == 0) ? cv.x : (c == 1) ? cv.y : (c == 2) ? cv.z : cv.w;
            float ev = __shfl(cand, (lane & 48) | ((yv & 63) >> 2));
            emB = ev * K_INVLN2 - lseB;
        }
        if (gl == 0) {
            if (ua <= Ue) outv[rowbase + ua] = make_float2(a1.x * K_INVLN2 - lseA, emA);
            if (ub <= Ue) outv[rowbase + ub] = make_float2(b1.x * K_INVLN2 - lseB, emB);
        }
    }
}

// Stage B: pair-condensation coefficients, PACKED (unchanged).
__global__ __launch_bounds__(256) void cond_kernel(
    const int* __restrict__ logit_lens, const int* __restrict__ y_lens,
    float* __restrict__ ws)
{
    const int b = blockIdx.x / 320;
    const int m = blockIdx.x - b * 320 + 1;
    if (m > ((logit_lens[b] - 1 + y_lens[b]) >> 1)) return;
    const int r1 = 2 * m - 2, r2 = 2 * m - 1;
    const float2* outv = (const float2*)(ws + OUT_OFF);

    __shared__ float2 D1[U1], D2[U1];
    __shared__ float pckS[PCKROW];
    for (int q = threadIdx.x; q < 2 * U1; q += 256) {
        const int which = q >= U1;
        const int j = q - which * U1;
        const int t = (which ? r2 : r1) - j;
        float2 val = make_float2(SENT, SENT);
        if (t >= 0 && t < Tt) val = outv[((size_t)b * Tt + t) * U1 + j];
        (which ? D2 : D1)[j] = val;
    }
    __syncthreads();

    const int u = threadIdx.x;
    if (u <= 128) {
        float2 d1  = D1[u], d2 = D2[u];
        float2 d1m = (u >= 1) ? D1[u - 1] : make_float2(SENT, SENT);
        float d2my  = (u >= 1) ? D2[u - 1].y : SENT;
        float d1m2y = (u >= 2) ? D1[u - 2].y : SENT;
        float A = d1.x + d2.x;
        float B = lae2(d1m.y + d2.x, d1m.x + d2my);
        float C = d1m2y + d2my;
        if (u < 128) {
            int base = (u >> 1) * 8 + (u & 1);
            pckS[base]     = A;
            pckS[base + 2] = B;
            pckS[base + 4] = C;
            if ((u & 1) == 0) { pckS[base + 6] = 0.0f; pckS[base + 7] = 0.0f; }
        } else {
            ((float4*)(ws + CTCOL_OFF))[(size_t)b * CTROWS + m] = make_float4(A, B, C, 0.0f);
        }
    }
    __syncthreads();

    float* pckG = ws + PCK_OFF + (size_t)b * PCKBSZ + (size_t)m * PCKROW;
    for (int i = threadIdx.x; i < PCKROW; i += 256) pckG[i] = pckS[i];
}

// Stage C: k=4 condensation; emits FORWARD records (as r22) AND BACKWARD
// (transposed) records: bw lane l = {W0[2l],W1[2l+1],W2[2l+2],W3[2l+3] |
// W4[2l+4],W0[2l+1],W1[2l+2],W2[2l+3] | W3[2l+4],W4[2l+5],c5x,c5y}, source
// slots >127 -> SENT (u=128 row handled via c5 terms + WCOL W0).
__global__ __launch_bounds__(256) void compose_kernel(
    const int* __restrict__ logit_lens, const int* __restrict__ y_lens,
    float* __restrict__ ws)
{
    const int b = blockIdx.x / 159;
    const int q = blockIdx.x - b * 159 + 1;        // 1..159
    const int dend = logit_lens[b] - 1 + y_lens[b];
    if (4 * q > dend) return;
    const int m1 = 2 * q - 1, m2 = 2 * q;
    const float* PCKb = ws + PCK_OFF + (size_t)b * PCKBSZ;
    const float4* COLb = (const float4*)(ws + CTCOL_OFF) + (size_t)b * CTROWS;

    __shared__ float a1s[131], b1s[131], c1s[131];
    __shared__ float wrk[WROWF], wrkB[WROWF];
    __shared__ float sW0[129], sW1[129], sW2[129], sW3[129], sW4[129];
    const int u = threadIdx.x;
    if (u < 2) { a1s[u] = SENT; b1s[u] = SENT; c1s[u] = SENT; }
    if (u < 128) {
        const float* p = PCKb + (size_t)m1 * PCKROW + (u >> 1) * 8;
        int par = u & 1;
        a1s[u + 2] = p[par]; b1s[u + 2] = p[2 + par]; c1s[u + 2] = p[4 + par];
    } else if (u == 128) {
        float4 cc = COLb[m1];
        a1s[130] = cc.x; b1s[130] = cc.y; c1s[130] = cc.z;
    }
    __syncthreads();

    if (u <= 128) {
        float A2, B2, C2;
        if (u < 128) {
            const float* p = PCKb + (size_t)m2 * PCKROW + (u >> 1) * 8;
            int par = u & 1;
            A2 = p[par]; B2 = p[2 + par]; C2 = p[4 + par];
        } else {
            float4 cc = COLb[m2];
            A2 = cc.x; B2 = cc.y; C2 = cc.z;
        }
        float A1 = a1s[u + 2], A1m = a1s[u + 1], A1m2 = a1s[u];
        float B1 = b1s[u + 2], B1m = b1s[u + 1], B1m2 = b1s[u];
        float C1 = c1s[u + 2], C1m = c1s[u + 1], C1m2 = c1s[u];
        float W0 = A2 + A1;
        float W1 = lae2(A2 + B1, B2 + A1m);
        float W2 = lae3(A2 + C1, B2 + B1m, C2 + A1m2);
        float W3 = lae2(B2 + C1m, C2 + B1m2);
        float W4 = C2 + C1m2;
        sW0[u] = W0; sW1[u] = W1; sW2[u] = W2; sW3[u] = W3; sW4[u] = W4;
        if (u < 128) {
            int base = (u >> 1) * 12 + (u & 1);
            wrk[base]     = W0;
            wrk[base + 2] = W1;
            wrk[base + 4] = W2;
            wrk[base + 6] = W3;
            wrk[base + 8] = W4;
            if ((u & 1) == 0) { wrk[base + 10] = 0.0f; wrk[base + 11] = 0.0f; }
        } else {
            float* wc = ws + WCOL_OFF + ((size_t)b * WROWS + q) * 8;
            wc[0] = W0; wc[1] = W1; wc[2] = W2; wc[3] = W3; wc[4] = W4;
            wc[5] = 0.0f; wc[6] = 0.0f; wc[7] = 0.0f;
        }
    }
    __syncthreads();

    if (u < 64) {
        const int l = u, e = 2 * l;
        float cx2 = (e + 2 <= 127) ? sW2[e + 2] : SENT;
        float cx3 = (e + 3 <= 127) ? sW3[e + 3] : SENT;
        float cx4 = (e + 4 <= 127) ? sW4[e + 4] : SENT;
        float cy1 = (e + 2 <= 127) ? sW1[e + 2] : SENT;
        float cy2 = (e + 3 <= 127) ? sW2[e + 3] : SENT;
        float cy3 = (e + 4 <= 127) ? sW3[e + 4] : SENT;
        float cy4 = (e + 5 <= 127) ? sW4[e + 5] : SENT;
        float c5x = (l == 62) ? sW4[128] : (l == 63) ? sW2[128] : SENT;
        float c5y = (l == 62) ? sW3[128] : (l == 63) ? sW1[128] : SENT;
        float* rb = wrkB + l * 12;
        rb[0] = sW0[e];     rb[1] = sW1[e + 1]; rb[2]  = cx2; rb[3]  = cx3;
        rb[4] = cx4;        rb[5] = sW0[e + 1]; rb[6]  = cy1; rb[7]  = cy2;
        rb[8] = cy3;        rb[9] = cy4;        rb[10] = c5x; rb[11] = c5y;
    }
    __syncthreads();

    float* wg  = ws + W_OFF  + (size_t)b * WBSZ + (size_t)q * WROWF;
    float* wbg = ws + WB_OFF + (size_t)b * WBSZ + (size_t)q * WROWF;
    for (int i = threadIdx.x; i < WROWF; i += 256) { wg[i] = wrk[i]; wbg[i] = wrkB[i]; }
}

// rotate up: lane i <- lane i-1. MODE 0/1: DPP (runtime-verified), 2: shuffle.
template<int MODE>
__device__ __forceinline__ float rotU(float x, int lane) {
    if constexpr (MODE == 2) {
        return __shfl(x, (lane + 63) & 63);
    } else {
        constexpr int CTRL = (MODE == 0) ? 0x13C : 0x134;
        int i = __builtin_bit_cast(int, x);
        i = __builtin_amdgcn_update_dpp(i, i, CTRL, 0xF, 0xF, true);
        return __builtin_bit_cast(float, i);
    }
}
// rotate down: lane i <- lane i+1.
template<int MODE>
__device__ __forceinline__ float rotD(float x, int lane) {
    if constexpr (MODE == 2) {
        return __shfl(x, (lane + 1) & 63);
    } else {
        constexpr int CTRL = (MODE == 0) ? 0x134 : 0x13C;
        int i = __builtin_bit_cast(int, x);
        i = __builtin_amdgcn_update_dpp(i, i, CTRL, 0xF, 0xF, true);
        return __builtin_bit_cast(float, i);
    }
}

// FORWARD half: q = 1..qmid (r22 body, tails removed), store alpha state.
template<int MODE, bool H128>
__device__ __forceinline__ void fw_body(int b, int lane, int Tb, int Ub,
                                        float* __restrict__ ws)
{
    const float* WTb = ws + W_OFF + (size_t)b * WBSZ;
    const float* WCb = ws + WCOL_OFF + (size_t)b * WROWS * 8;
    int zv; asm volatile("v_mov_b32 %0, 0" : "=v"(zv));

    float px = (lane == 0) ? 0.0f : SENT;
    float py = SENT, p2 = SENT;
    const int dend = Tb - 1 + Ub;
    const int nq   = dend >> 2;
    const int qend = nq >> 1;          // qmid

    float4 A0,A1,A2,A3,A4,A5,A6,A7;
    float4 B0,B1,B2,B3,B4,B5,B6,B7;
    float2 C0,C1,C2,C3,C4,C5,C6,C7;
    float4 Oa0,Oa1,Oa2,Oa3,Oa4,Oa5,Oa6,Oa7;
    float2 Oc0,Oc1,Oc2,Oc3,Oc4,Oc5,Oc6,Oc7;

#define LOADW(i, qq) { unsigned o = (unsigned)(qq) * WROWF + lane * 12; \
    A##i = *(const float4*)(WTb + o); \
    B##i = *(const float4*)(WTb + o + 4); \
    C##i = *(const float2*)(WTb + o + 8); \
    if constexpr (H128) { \
        Oa##i = *(const float4*)(WCb + (qq) * 8 + zv); \
        Oc##i = *(const float2*)(WCb + (qq) * 8 + 4 + zv); } }

#define PIN(i) if constexpr (H128) { \
        asm volatile("" : "+v"(A##i.x), "+v"(A##i.y), "+v"(A##i.z), "+v"(A##i.w), \
                          "+v"(B##i.x), "+v"(B##i.y), "+v"(B##i.z), "+v"(B##i.w), \
                          "+v"(C##i.x), "+v"(C##i.y), \
                          "+v"(Oa##i.x), "+v"(Oa##i.y), "+v"(Oa##i.z), "+v"(Oa##i.w), \
                          "+v"(Oc##i.x)); \
    } else { \
        asm volatile("" : "+v"(A##i.x), "+v"(A##i.y), "+v"(A##i.z), "+v"(A##i.w), \
                          "+v"(B##i.x), "+v"(B##i.y), "+v"(B##i.z), "+v"(B##i.w), \
                          "+v"(C##i.x), "+v"(C##i.y)); \
    }

#define COMP4(i) { \
    float p1y = rotU<MODE>(py, lane); \
    float p1x = rotU<MODE>(px, lane); \
    float p2y = rotU<MODE>(p1y, lane); \
    float p2x = rotU<MODE>(p1x, lane); \
    float nx = lae5(px + A##i.x, p1y + A##i.z, p1x + B##i.x, p2y + B##i.z, p2x + C##i.x); \
    float ny = lae5(py + A##i.y, px + A##i.w, p1y + B##i.y, p1x + B##i.w, p2y + C##i.y); \
    if constexpr (H128) p2 = lae5(p2 + Oa##i.x, p1y + Oa##i.y, p1x + Oa##i.z, \
                                  p2y + Oa##i.w, p2x + Oc##i.x); \
    px = nx; py = ny; }

    LOADW(0,1) LOADW(1,2) LOADW(2,3) LOADW(3,4)
    LOADW(4,5) LOADW(5,6) LOADW(6,7) LOADW(7,8)

    int q = 1;
    for (; q + 7 <= qend; q += 8) {
        PIN(0) COMP4(0) { int dn = q + 8  > qend ? qend : q + 8;  LOADW(0, dn) }
        PIN(1) COMP4(1) { int dn = q + 9  > qend ? qend : q + 9;  LOADW(1, dn) }
        PIN(2) COMP4(2) { int dn = q + 10 > qend ? qend : q + 10; LOADW(2, dn) }
        PIN(3) COMP4(3) { int dn = q + 11 > qend ? qend : q + 11; LOADW(3, dn) }
        PIN(4) COMP4(4) { int dn = q + 12 > qend ? qend : q + 12; LOADW(4, dn) }
        PIN(5) COMP4(5) { int dn = q + 13 > qend ? qend : q + 13; LOADW(5, dn) }
        PIN(6) COMP4(6) { int dn = q + 14 > qend ? qend : q + 14; LOADW(6, dn) }
        PIN(7) COMP4(7) { int dn = q + 15 > qend ? qend : q + 15; LOADW(7, dn) }
    }
#define TAILW(i) if (q <= qend) { PIN(i) COMP4(i) q++; }
    TAILW(0) TAILW(1) TAILW(2) TAILW(3) TAILW(4) TAILW(5) TAILW(6)

    float* F = ws + ST_OFF + (size_t)b * 260;
    ((float2*)F)[lane] = make_float2(px, py);
    if (lane == 0) F[128] = H128 ? p2 : SENT;
#undef LOADW
#undef PIN
#undef COMP4
#undef TAILW
}

// BACKWARD half: tails^T, then P_q^T for q = nq..qmid+1; store beta state.
template<int MODE>
__device__ __forceinline__ void bw_body(int b, int lane, int Tb, int Ub,
                                        float* __restrict__ ws)
{
    const float2* outv = (const float2*)(ws + OUT_OFF);
    const float* PCKb = ws + PCK_OFF + (size_t)b * PCKBSZ;
    const float4* COLb = (const float4*)(ws + CTCOL_OFF) + (size_t)b * CTROWS;
    const float* WBb = ws + WB_OFF + (size_t)b * WBSZ;
    const float* WCb = ws + WCOL_OFF + (size_t)b * WROWS * 8;
    int zv; asm volatile("v_mov_b32 %0, 0" : "=v"(zv));

    const int dend = Tb - 1 + Ub;
    const int nq   = dend >> 2;
    const int qlo  = (nq >> 1) + 1;    // down to qmid+1
    const int rem  = dend & 3;

    // seed beta at diag dend: e_{Ub}
    float wx = SENT, wy = SENT, w128 = SENT;
    if (Ub == 128) w128 = 0.0f;
    else if (lane == (Ub >> 1)) { if (Ub & 1) wy = 0.0f; else wx = 0.0f; }

    float4 X0,X1,X2,X3,X4,X5,X6,X7;
    float4 Y0,Y1,Y2,Y3,Y4,Y5,Y6,Y7;
    float4 Z0,Z1,Z2,Z3,Z4,Z5,Z6,Z7;
    float w0c0,w0c1,w0c2,w0c3,w0c4,w0c5,w0c6,w0c7;

#define LOADB(i, qq) { unsigned o = (unsigned)(qq) * WROWF + lane * 12; \
    X##i = *(const float4*)(WBb + o); \
    Y##i = *(const float4*)(WBb + o + 4); \
    Z##i = *(const float4*)(WBb + o + 8); \
    w0c##i = *(WCb + (qq) * 8 + zv); }

#define PINB(i) asm volatile("" : "+v"(X##i.x), "+v"(X##i.y), "+v"(X##i.z), "+v"(X##i.w), \
                          "+v"(Y##i.x), "+v"(Y##i.y), "+v"(Y##i.z), "+v"(Y##i.w), \
                          "+v"(Z##i.x), "+v"(Z##i.y), "+v"(Z##i.z), "+v"(Z##i.w), \
                          "+v"(w0c##i));

#define CLD(v) ((v) < qlo ? qlo : (v))
    LOADB(0, CLD(nq))     LOADB(1, CLD(nq - 1)) LOADB(2, CLD(nq - 2)) LOADB(3, CLD(nq - 3))
    LOADB(4, CLD(nq - 4)) LOADB(5, CLD(nq - 5)) LOADB(6, CLD(nq - 6)) LOADB(7, CLD(nq - 7))

    // ---- tail transposes (single^T first, then pair^T; forward order was pair,single) ----
    if (rem & 1) {
        const int r = dend - 1;
        int j1 = 2 * lane, j2 = 2 * lane + 1;
        int t1 = r - j1; t1 = t1 > Tt - 1 ? Tt - 1 : t1; if (t1 < 0) t1 = 0;
        int t2 = r - j2; t2 = t2 > Tt - 1 ? Tt - 1 : t2; if (t2 < 0) t2 = 0;
        float2 F1 = outv[((size_t)b * Tt + t1) * U1 + j1];
        float2 F2 = outv[((size_t)b * Tt + t2) * U1 + j2];
        int tg = r - 128; if (tg < 0) tg = 0;
        float2 G = outv[((size_t)b * Tt + tg) * U1 + 128];
        float n1x = rotD<MODE>(wx, lane);
        float nx = lae2(F1.x + wx, F1.y + wy);
        float ny = lae2(F2.x + wy, F2.y + ((lane == 63) ? w128 : n1x));
        w128 = G.x + w128;
        wx = nx; wy = ny;
    }
    if (rem >= 2) {
        const int mpair = 2 * nq + 1;
        const float* prow = PCKb + (size_t)mpair * PCKROW;
        float4 Qp  = *(const float4*)(prow + (lane << 3));
        float2 Rp  = *(const float2*)(prow + (lane << 3) + 4);
        int lp = lane + 1 > 63 ? 63 : lane + 1;
        float4 QpN = *(const float4*)(prow + (lp << 3));
        float2 RpN = *(const float2*)(prow + (lp << 3) + 4);
        float4 Op  = COLb[mpair + zv];
        float n1x = rotD<MODE>(wx, lane), n1y = rotD<MODE>(wy, lane);
        float nx = lae3(Qp.x + wx, Qp.w + wy,
                        (lane == 63) ? (Op.z + w128) : (RpN.x + n1x));
        float ny = lae3(Qp.y + wy,
                        (lane == 63) ? (Op.y + w128) : (QpN.z + n1x),
                        (lane == 63) ? SENT : (RpN.y + n1y));
        w128 = Op.x + w128;
        wx = nx; wy = ny;
    }

    // ---- condensed transposed steps ----
#define COMPB(i) { \
    float n1x = rotD<MODE>(wx, lane), n1y = rotD<MODE>(wy, lane); \
    float n2x = rotD<MODE>(n1x, lane), n2y = rotD<MODE>(n1y, lane); \
    float nx = lae6(wx + X##i.x, wy + X##i.y, n1x + X##i.z, n1y + X##i.w, \
                    n2x + Y##i.x, Z##i.z + w128); \
    float ny = lae6(wy + Y##i.y, n1x + Y##i.z, n1y + Y##i.w, n2x + Z##i.x, \
                    n2y + Z##i.y, Z##i.w + w128); \
    w128 = w0c##i + w128; \
    wx = nx; wy = ny; }

    int q = nq;
    for (; q - 7 >= qlo; q -= 8) {
        PINB(0) COMPB(0) LOADB(0, CLD(q - 8))
        PINB(1) COMPB(1) LOADB(1, CLD(q - 9))
        PINB(2) COMPB(2) LOADB(2, CLD(q - 10))
        PINB(3) COMPB(3) LOADB(3, CLD(q - 11))
        PINB(4) COMPB(4) LOADB(4, CLD(q - 12))
        PINB(5) COMPB(5) LOADB(5, CLD(q - 13))
        PINB(6) COMPB(6) LOADB(6, CLD(q - 14))
        PINB(7) COMPB(7) LOADB(7, CLD(q - 15))
    }
#define TAILB(i) if (q >= qlo) { PINB(i) COMPB(i) q--; }
    TAILB(0) TAILB(1) TAILB(2) TAILB(3) TAILB(4) TAILB(5) TAILB(6)

    float* Bst = ws + ST_OFF + (size_t)b * 260 + 130;
    ((float2*)Bst)[lane] = make_float2(wx, wy);
    if (lane == 0) Bst[128] = w128;
#undef LOADB
#undef PINB
#undef CLD
#undef COMPB
#undef TAILB
}

__global__ __launch_bounds__(64) void dp_kernel(
    const int* __restrict__ logit_lens, const int* __restrict__ y_lens,
    float* __restrict__ ws)
{
    const int b   = blockIdx.x >> 1;
    const int dir = blockIdx.x & 1;
    const int lane = threadIdx.x;
    const int Tb = logit_lens[b];
    const int Ub = y_lens[b];
    const bool h = (Ub == 128);
    int li = lane;
    int r0 = __builtin_amdgcn_update_dpp(li, li, 0x13C, 0xF, 0xF, true);
    int r1 = __builtin_amdgcn_update_dpp(li, li, 0x134, 0xF, 0xF, true);
    int wantU = (lane + 63) & 63, wantD = (lane + 1) & 63;
    int mode = 2;
    if (__all(r0 == wantU) && __all(r1 == wantD)) mode = 0;
    else if (__all(r1 == wantU) && __all(r0 == wantD)) mode = 1;

    if (dir == 0) {
        if (mode == 0)      { if (h) fw_body<0, true>(b, lane, Tb, Ub, ws); else fw_body<0, false>(b, lane, Tb, Ub, ws); }
        else if (mode == 1) { if (h) fw_body<1, true>(b, lane, Tb, Ub, ws); else fw_body<1, false>(b, lane, Tb, Ub, ws); }
        else                { if (h) fw_body<2, true>(b, lane, Tb, Ub, ws); else fw_body<2, false>(b, lane, Tb, Ub, ws); }
    } else {
        if (mode == 0)      bw_body<0>(b, lane, Tb, Ub, ws);
        else if (mode == 1) bw_body<1>(b, lane, Tb, Ub, ws);
        else                bw_body<2>(b, lane, Tb, Ub, ws);
    }
}

// Combine: ll = lae_u(alpha_mid[u] + beta_mid[u]); res = -(ll + final_blank)*ln2
__global__ __launch_bounds__(64) void combine_kernel(
    const int* __restrict__ logit_lens, const int* __restrict__ y_lens,
    float* __restrict__ ws)
{
    const int b = blockIdx.x;
    const int lane = threadIdx.x;
    const float* F = ws + ST_OFF + (size_t)b * 260;
    const float* Bs = F + 130;
    float2 v = ((const float2*)F)[lane];
    float2 w = ((const float2*)Bs)[lane];
    float r = lae2(v.x + w.x, v.y + w.y);
    #pragma unroll
    for (int off = 32; off; off >>= 1)
        r = lae2(r, __shfl_xor(r, off));
    r = lae2(r, F[128] + Bs[128]);
    const int Tb = logit_lens[b], Ub = y_lens[b];
    const float2* outv = (const float2*)(ws + OUT_OFF);
    float pbf = outv[((size_t)b * Tt + (Tb - 1)) * U1 + Ub].x;
    if (lane == 0)
        ws[RES_OFF + b] = -(r + pbf) * K_LN2;
}

__global__ void mean_kernel(const float* __restrict__ res, float* __restrict__ out)
{
    if (threadIdx.x == 0) {
        float s = 0.0f;
        #pragma unroll
        for (int i = 0; i < Bb; ++i) s += res[i];
        out[0] = s * (1.0f / Bb);
    }
}

extern "C" void kernel_launch(void* const* d_in, const int* in_sizes, int n_in,
                              void* d_out, int out_size, void* d_ws, size_t ws_size,
                              hipStream_t stream) {
    const float* logits     = (const float*)d_in[0];
    const int*   y          = (const int*)d_in[1];
    const int*   logit_lens = (const int*)d_in[2];
    const int*   y_lens     = (const int*)d_in[3];
    float* ws  = (float*)d_ws;
    float* out = (float*)d_out;

    dim3 lgrid(Tt, Bb);
    lse_kernel<<<lgrid, 256, 0, stream>>>(logits, y, logit_lens, y_lens, ws);
    cond_kernel<<<Bb * 320, 256, 0, stream>>>(logit_lens, y_lens, ws);
    compose_kernel<<<Bb * 159, 256, 0, stream>>>(logit_lens, y_lens, ws);
    dp_kernel<<<Bb * 2, 64, 0, stream>>>(logit_lens, y_lens, ws);
    combine_kernel<<<Bb, 64, 0, stream>>>(logit_lens, y_lens, ws);
    mean_kernel<<<1, 64, 0, stream>>>(ws + RES_OFF, out);
}

// Round 25
// 58.300 us; speedup vs baseline: 1.6278x; 1.1071x over previous
//
#include <hip/hip_runtime.h>

#define Bb 8
#define Tt 512
#define Uu 128
#define U1 129
#define Vv 128

#define OUT_OFF 0                          // float2 OUT[b][t][u] linear
#define CTROWS 321                         // pair rows m (only mpair used now)
#define PCKROW 512                         // floats per packed pair row (64 lanes x 8)
#define PCKBSZ ((size_t)CTROWS * PCKROW)
#define PCK_OFF ((size_t)Bb * Tt * U1 * 2)
#define CTCOL_OFF (PCK_OFF + (size_t)Bb * PCKBSZ)      // float4 {A,B,C,0}[b][m]
#define WROWF 768                          // 64 lanes x 12 floats
#define WROWS 161
#define WBSZ ((size_t)WROWS * WROWF)
#define W_OFF (CTCOL_OFF + (size_t)Bb * CTROWS * 4)    // forward k=4 records
#define WCOL_OFF (W_OFF + (size_t)Bb * WBSZ)           // 8 floats per (b,q): u=128 row
#define WB_OFF (WCOL_OFF + (size_t)Bb * WROWS * 8)     // backward (transposed) records
#define ST_OFF (WB_OFF + (size_t)Bb * WBSZ)            // per b: fw 130 floats, bw 130
#define RES_OFF (ST_OFF + (size_t)Bb * 260)

#define K_LN2    0.6931471805599453f
#define K_INVLN2 1.4426950408889634f
#define SENT (-1.0e30f)                    // finite sentinel; exp2(-big)=0, no inf/NaN

__device__ __forceinline__ float fexp2(float x) {
    float r; asm("v_exp_f32 %0, %1" : "=v"(r) : "v"(x)); return r;
}
__device__ __forceinline__ float flog2(float x) {
    float r; asm("v_log_f32 %0, %1" : "=v"(r) : "v"(x)); return r;
}
__device__ __forceinline__ float fmax3(float x, float y, float z) {
    float r; asm("v_max3_f32 %0, %1, %2, %3" : "=v"(r) : "v"(x), "v"(y), "v"(z));
    return r;
}
__device__ __forceinline__ float lae2(float x, float y) {
    float dd = x - y;
    float nad = __builtin_bit_cast(float, __builtin_bit_cast(int, dd) | 0x80000000);
    return fmaxf(x, y) + flog2(1.0f + fexp2(nad));
}
__device__ __forceinline__ float lae3(float x, float y, float z) {
    float m = fmax3(x, y, z);
    return m + flog2(fexp2(x - m) + fexp2(y - m) + fexp2(z - m));
}
__device__ __forceinline__ float lae5(float a, float b, float c, float d, float e) {
    float m = fmax3(a, b, c);
    m = fmax3(m, d, e);
    return m + flog2(fexp2(a - m) + fexp2(b - m) + fexp2(c - m)
                   + fexp2(d - m) + fexp2(e - m));
}
__device__ __forceinline__ float lae6(float a, float b, float c, float d, float e, float f) {
    float m = fmaxf(fmax3(a, b, c), fmax3(d, e, f));
    return m + flog2(fexp2(a - m) + fexp2(b - m) + fexp2(c - m)
                   + fexp2(d - m) + fexp2(e - m) + fexp2(f - m));
}

// Stage A: band-restricted streaming LSE (unchanged).
__global__ __launch_bounds__(256) void lse_kernel(
    const float* __restrict__ logits, const int* __restrict__ y,
    const int* __restrict__ logit_lens, const int* __restrict__ y_lens,
    float* __restrict__ ws)
{
    const int b = blockIdx.y;
    const int t = blockIdx.x;
    if (t >= logit_lens[b]) return;
    const int Ue = y_lens[b];

    float2* outv = (float2*)(ws + OUT_OFF);
    const int wid  = threadIdx.x >> 6;
    const int lane = threadIdx.x & 63;
    const int g    = lane >> 4;
    const int gl   = lane & 15;
    const unsigned rowbase = ((unsigned)b * Tt + t) * U1;
    const int yb = b * Uu;

    for (int u0 = wid * 8; u0 <= Ue; u0 += 32) {
        const int ua = u0 + g;
        const int ub = u0 + 4 + g;
        const int uca = ua > Ue ? Ue : ua;
        const int ucb = ub > Ue ? Ue : ub;
        const float* pa = logits + (size_t)(rowbase + uca) * Vv;
        const float* pb = logits + (size_t)(rowbase + ucb) * Vv;
        float4 a1 = *(const float4*)(pa + gl * 4);
        float4 a2 = *(const float4*)(pa + 64 + gl * 4);
        float4 b1 = *(const float4*)(pb + gl * 4);
        float4 b2 = *(const float4*)(pb + 64 + gl * 4);

        float sa = (fexp2(a1.x * K_INVLN2) + fexp2(a1.y * K_INVLN2))
                 + (fexp2(a1.z * K_INVLN2) + fexp2(a1.w * K_INVLN2))
                 + (fexp2(a2.x * K_INVLN2) + fexp2(a2.y * K_INVLN2))
                 + (fexp2(a2.z * K_INVLN2) + fexp2(a2.w * K_INVLN2));
        float sb = (fexp2(b1.x * K_INVLN2) + fexp2(b1.y * K_INVLN2))
                 + (fexp2(b1.z * K_INVLN2) + fexp2(b1.w * K_INVLN2))
                 + (fexp2(b2.x * K_INVLN2) + fexp2(b2.y * K_INVLN2))
                 + (fexp2(b2.z * K_INVLN2) + fexp2(b2.w * K_INVLN2));
        #pragma unroll
        for (int off = 8; off; off >>= 1) {
            sa += __shfl_xor(sa, off);
            sb += __shfl_xor(sb, off);
        }
        float lseA = flog2(sa);
        float lseB = flog2(sb);

        float emA = SENT, emB = SENT;
        if (uca < Uu) {
            int yv = y[yb + uca];
            int c = yv & 3;
            float4 cv = (yv & 64) ? a2 : a1;
            float cand = (c == 0) ? cv.x : (c == 1) ? cv.y : (c == 2) ? cv.z : cv.w;
            float ev = __shfl(cand, (lane & 48) | ((yv & 63) >> 2));
            emA = ev * K_INVLN2 - lseA;
        }
        if (ucb < Uu) {
            int yv = y[yb + ucb];
            int c = yv & 3;
            float4 cv = (yv & 64) ? b2 : b1;
            float cand = (c == 0) ? cv.x : (c == 1) ? cv.y : (c == 2) ? cv.z : cv.w;
            float ev = __shfl(cand, (lane & 48) | ((yv & 63) >> 2));
            emB = ev * K_INVLN2 - lseB;
        }
        if (gl == 0) {
            if (ua <= Ue) outv[rowbase + ua] = make_float2(a1.x * K_INVLN2 - lseA, emA);
            if (ub <= Ue) outv[rowbase + ub] = make_float2(b1.x * K_INVLN2 - lseB, emB);
        }
    }
}

// Stage B+C fused: compose pair matrices m1=2q-1, m2=2q DIRECTLY from OUT
// (cond's coefficient formulas inlined -> bit-identical values, no PCK
// round-trip). Emits forward W records + backward (transposed) records.
// Extra branch: q = nq+1 writes ONLY the packed pair row m1 = mpair = 2nq+1
// (+ its CTCOL entry) needed by bw's pair-tail.
__global__ __launch_bounds__(256) void compose_kernel(
    const int* __restrict__ logit_lens, const int* __restrict__ y_lens,
    float* __restrict__ ws)
{
    const int b = blockIdx.x / 160;
    const int q = blockIdx.x - b * 160 + 1;        // 1..160
    const int dend = logit_lens[b] - 1 + y_lens[b];
    const int nq = dend >> 2;
    const bool full = (4 * q <= dend);
    const bool pair_only = (!full) && (q == nq + 1);
    if (!full && !pair_only) return;
    const float2* outv = (const float2*)(ws + OUT_OFF);

    __shared__ float2 D[4][U1];
    __shared__ float a1s[131], b1s[131], c1s[131];
    __shared__ float wrk[WROWF], wrkB[WROWF];
    __shared__ float sW0[129], sW1[129], sW2[129], sW3[129], sW4[129];
    __shared__ float pckS[PCKROW];
    const int u = threadIdx.x;

    for (int i = threadIdx.x; i < 4 * U1; i += 256) {
        int row = i / U1, j = i - row * U1;
        int r = 4 * (q - 1) + row;
        int t = r - j;
        D[row][j] = (t >= 0 && t < Tt) ? outv[((size_t)b * Tt + t) * U1 + j]
                                       : make_float2(SENT, SENT);
    }
    __syncthreads();

    // pair m1 coeffs -> a1s/b1s/c1s (+2 offset); pair m2 coeffs -> registers
    float A2r = SENT, B2r = SENT, C2r = SENT;
    if (u < 2) { a1s[u] = SENT; b1s[u] = SENT; c1s[u] = SENT; }
    if (u <= 128) {
        float2 d1 = D[0][u], d2 = D[1][u];
        float2 d1m = (u >= 1) ? D[0][u - 1] : make_float2(SENT, SENT);
        float d2my  = (u >= 1) ? D[1][u - 1].y : SENT;
        float d1m2y = (u >= 2) ? D[0][u - 2].y : SENT;
        a1s[u + 2] = d1.x + d2.x;
        b1s[u + 2] = lae2(d1m.y + d2.x, d1m.x + d2my);
        c1s[u + 2] = d1m2y + d2my;
        float2 e1 = D[2][u], e2 = D[3][u];
        float2 e1m = (u >= 1) ? D[2][u - 1] : make_float2(SENT, SENT);
        float e2my  = (u >= 1) ? D[3][u - 1].y : SENT;
        float e1m2y = (u >= 2) ? D[2][u - 2].y : SENT;
        A2r = e1.x + e2.x;
        B2r = lae2(e1m.y + e2.x, e1m.x + e2my);
        C2r = e1m2y + e2my;
    }
    __syncthreads();

    if (pair_only) {
        if (u <= 128) {
            float A = a1s[u + 2], B = b1s[u + 2], C = c1s[u + 2];
            if (u < 128) {
                int base = (u >> 1) * 8 + (u & 1);
                pckS[base]     = A;
                pckS[base + 2] = B;
                pckS[base + 4] = C;
                if ((u & 1) == 0) { pckS[base + 6] = 0.0f; pckS[base + 7] = 0.0f; }
            } else {
                ((float4*)(ws + CTCOL_OFF))[(size_t)b * CTROWS + (2 * q - 1)]
                    = make_float4(A, B, C, 0.0f);
            }
        }
        __syncthreads();
        float* pckG = ws + PCK_OFF + (size_t)b * PCKBSZ + (size_t)(2 * q - 1) * PCKROW;
        for (int i = threadIdx.x; i < PCKROW; i += 256) pckG[i] = pckS[i];
        return;
    }

    if (u <= 128) {
        float A1 = a1s[u + 2], A1m = a1s[u + 1], A1m2 = a1s[u];
        float B1 = b1s[u + 2], B1m = b1s[u + 1], B1m2 = b1s[u];
        float C1 = c1s[u + 2], C1m = c1s[u + 1], C1m2 = c1s[u];
        float W0 = A2r + A1;
        float W1 = lae2(A2r + B1, B2r + A1m);
        float W2 = lae3(A2r + C1, B2r + B1m, C2r + A1m2);
        float W3 = lae2(B2r + C1m, C2r + B1m2);
        float W4 = C2r + C1m2;
        sW0[u] = W0; sW1[u] = W1; sW2[u] = W2; sW3[u] = W3; sW4[u] = W4;
        if (u < 128) {
            int base = (u >> 1) * 12 + (u & 1);
            wrk[base]     = W0;
            wrk[base + 2] = W1;
            wrk[base + 4] = W2;
            wrk[base + 6] = W3;
            wrk[base + 8] = W4;
            if ((u & 1) == 0) { wrk[base + 10] = 0.0f; wrk[base + 11] = 0.0f; }
        } else {
            float* wc = ws + WCOL_OFF + ((size_t)b * WROWS + q) * 8;
            wc[0] = W0; wc[1] = W1; wc[2] = W2; wc[3] = W3; wc[4] = W4;
            wc[5] = 0.0f; wc[6] = 0.0f; wc[7] = 0.0f;
        }
    }
    __syncthreads();

    if (u < 64) {
        const int l = u, e = 2 * l;
        float cx2 = (e + 2 <= 127) ? sW2[e + 2] : SENT;
        float cx3 = (e + 3 <= 127) ? sW3[e + 3] : SENT;
        float cx4 = (e + 4 <= 127) ? sW4[e + 4] : SENT;
        float cy1 = (e + 2 <= 127) ? sW1[e + 2] : SENT;
        float cy2 = (e + 3 <= 127) ? sW2[e + 3] : SENT;
        float cy3 = (e + 4 <= 127) ? sW3[e + 4] : SENT;
        float cy4 = (e + 5 <= 127) ? sW4[e + 5] : SENT;
        float c5x = (l == 62) ? sW4[128] : (l == 63) ? sW2[128] : SENT;
        float c5y = (l == 62) ? sW3[128] : (l == 63) ? sW1[128] : SENT;
        float* rb = wrkB + l * 12;
        rb[0] = sW0[e];     rb[1] = sW1[e + 1]; rb[2]  = cx2; rb[3]  = cx3;
        rb[4] = cx4;        rb[5] = sW0[e + 1]; rb[6]  = cy1; rb[7]  = cy2;
        rb[8] = cy3;        rb[9] = cy4;        rb[10] = c5x; rb[11] = c5y;
    }
    __syncthreads();

    float* wg  = ws + W_OFF  + (size_t)b * WBSZ + (size_t)q * WROWF;
    float* wbg = ws + WB_OFF + (size_t)b * WBSZ + (size_t)q * WROWF;
    for (int i = threadIdx.x; i < WROWF; i += 256) { wg[i] = wrk[i]; wbg[i] = wrkB[i]; }
}

// rotate up: lane i <- lane i-1. MODE 0/1: DPP (runtime-verified), 2: shuffle.
template<int MODE>
__device__ __forceinline__ float rotU(float x, int lane) {
    if constexpr (MODE == 2) {
        return __shfl(x, (lane + 63) & 63);
    } else {
        constexpr int CTRL = (MODE == 0) ? 0x13C : 0x134;
        int i = __builtin_bit_cast(int, x);
        i = __builtin_amdgcn_update_dpp(i, i, CTRL, 0xF, 0xF, true);
        return __builtin_bit_cast(float, i);
    }
}
// rotate down: lane i <- lane i+1.
template<int MODE>
__device__ __forceinline__ float rotD(float x, int lane) {
    if constexpr (MODE == 2) {
        return __shfl(x, (lane + 1) & 63);
    } else {
        constexpr int CTRL = (MODE == 0) ? 0x134 : 0x13C;
        int i = __builtin_bit_cast(int, x);
        i = __builtin_amdgcn_update_dpp(i, i, CTRL, 0xF, 0xF, true);
        return __builtin_bit_cast(float, i);
    }
}

// FORWARD half: q = 1..qmid, store alpha state. qmid = 8nq/15 (bw heavier).
template<int MODE, bool H128>
__device__ __forceinline__ void fw_body(int b, int lane, int Tb, int Ub,
                                        float* __restrict__ ws)
{
    const float* WTb = ws + W_OFF + (size_t)b * WBSZ;
    const float* WCb = ws + WCOL_OFF + (size_t)b * WROWS * 8;
    int zv; asm volatile("v_mov_b32 %0, 0" : "=v"(zv));

    float px = (lane == 0) ? 0.0f : SENT;
    float py = SENT, p2 = SENT;
    const int dend = Tb - 1 + Ub;
    const int nq   = dend >> 2;
    const int qend = (nq * 8) / 15;    // qmid

    float4 A0,A1,A2,A3,A4,A5,A6,A7;
    float4 B0,B1,B2,B3,B4,B5,B6,B7;
    float2 C0,C1,C2,C3,C4,C5,C6,C7;
    float4 Oa0,Oa1,Oa2,Oa3,Oa4,Oa5,Oa6,Oa7;
    float2 Oc0,Oc1,Oc2,Oc3,Oc4,Oc5,Oc6,Oc7;

#define LOADW(i, qq) { unsigned o = (unsigned)(qq) * WROWF + lane * 12; \
    A##i = *(const float4*)(WTb + o); \
    B##i = *(const float4*)(WTb + o + 4); \
    C##i = *(const float2*)(WTb + o + 8); \
    if constexpr (H128) { \
        Oa##i = *(const float4*)(WCb + (qq) * 8 + zv); \
        Oc##i = *(const float2*)(WCb + (qq) * 8 + 4 + zv); } }

#define PIN(i) if constexpr (H128) { \
        asm volatile("" : "+v"(A##i.x), "+v"(A##i.y), "+v"(A##i.z), "+v"(A##i.w), \
                          "+v"(B##i.x), "+v"(B##i.y), "+v"(B##i.z), "+v"(B##i.w), \
                          "+v"(C##i.x), "+v"(C##i.y), \
                          "+v"(Oa##i.x), "+v"(Oa##i.y), "+v"(Oa##i.z), "+v"(Oa##i.w), \
                          "+v"(Oc##i.x)); \
    } else { \
        asm volatile("" : "+v"(A##i.x), "+v"(A##i.y), "+v"(A##i.z), "+v"(A##i.w), \
                          "+v"(B##i.x), "+v"(B##i.y), "+v"(B##i.z), "+v"(B##i.w), \
                          "+v"(C##i.x), "+v"(C##i.y)); \
    }

#define COMP4(i) { \
    float p1y = rotU<MODE>(py, lane); \
    float p1x = rotU<MODE>(px, lane); \
    float p2y = rotU<MODE>(p1y, lane); \
    float p2x = rotU<MODE>(p1x, lane); \
    float nx = lae5(px + A##i.x, p1y + A##i.z, p1x + B##i.x, p2y + B##i.z, p2x + C##i.x); \
    float ny = lae5(py + A##i.y, px + A##i.w, p1y + B##i.y, p1x + B##i.w, p2y + C##i.y); \
    if constexpr (H128) p2 = lae5(p2 + Oa##i.x, p1y + Oa##i.y, p1x + Oa##i.z, \
                                  p2y + Oa##i.w, p2x + Oc##i.x); \
    px = nx; py = ny; }

    LOADW(0,1) LOADW(1,2) LOADW(2,3) LOADW(3,4)
    LOADW(4,5) LOADW(5,6) LOADW(6,7) LOADW(7,8)

    int q = 1;
    for (; q + 7 <= qend; q += 8) {
        PIN(0) COMP4(0) { int dn = q + 8  > qend ? qend : q + 8;  LOADW(0, dn) }
        PIN(1) COMP4(1) { int dn = q + 9  > qend ? qend : q + 9;  LOADW(1, dn) }
        PIN(2) COMP4(2) { int dn = q + 10 > qend ? qend : q + 10; LOADW(2, dn) }
        PIN(3) COMP4(3) { int dn = q + 11 > qend ? qend : q + 11; LOADW(3, dn) }
        PIN(4) COMP4(4) { int dn = q + 12 > qend ? qend : q + 12; LOADW(4, dn) }
        PIN(5) COMP4(5) { int dn = q + 13 > qend ? qend : q + 13; LOADW(5, dn) }
        PIN(6) COMP4(6) { int dn = q + 14 > qend ? qend : q + 14; LOADW(6, dn) }
        PIN(7) COMP4(7) { int dn = q + 15 > qend ? qend : q + 15; LOADW(7, dn) }
    }
#define TAILW(i) if (q <= qend) { PIN(i) COMP4(i) q++; }
    TAILW(0) TAILW(1) TAILW(2) TAILW(3) TAILW(4) TAILW(5) TAILW(6)

    float* F = ws + ST_OFF + (size_t)b * 260;
    ((float2*)F)[lane] = make_float2(px, py);
    if (lane == 0) F[128] = H128 ? p2 : SENT;
#undef LOADW
#undef PIN
#undef COMP4
#undef TAILW
}

// BACKWARD half: tails^T, then P_q^T for q = nq..qmid+1; store beta state.
template<int MODE>
__device__ __forceinline__ void bw_body(int b, int lane, int Tb, int Ub,
                                        float* __restrict__ ws)
{
    const float2* outv = (const float2*)(ws + OUT_OFF);
    const float* PCKb = ws + PCK_OFF + (size_t)b * PCKBSZ;
    const float4* COLb = (const float4*)(ws + CTCOL_OFF) + (size_t)b * CTROWS;
    const float* WBb = ws + WB_OFF + (size_t)b * WBSZ;
    const float* WCb = ws + WCOL_OFF + (size_t)b * WROWS * 8;
    int zv; asm volatile("v_mov_b32 %0, 0" : "=v"(zv));

    const int dend = Tb - 1 + Ub;
    const int nq   = dend >> 2;
    const int qlo  = (nq * 8) / 15 + 1;    // qmid + 1
    const int rem  = dend & 3;

    float wx = SENT, wy = SENT, w128 = SENT;
    if (Ub == 128) w128 = 0.0f;
    else if (lane == (Ub >> 1)) { if (Ub & 1) wy = 0.0f; else wx = 0.0f; }

    float4 X0,X1,X2,X3,X4,X5,X6,X7;
    float4 Y0,Y1,Y2,Y3,Y4,Y5,Y6,Y7;
    float4 Z0,Z1,Z2,Z3,Z4,Z5,Z6,Z7;
    float w0c0,w0c1,w0c2,w0c3,w0c4,w0c5,w0c6,w0c7;

#define LOADB(i, qq) { unsigned o = (unsigned)(qq) * WROWF + lane * 12; \
    X##i = *(const float4*)(WBb + o); \
    Y##i = *(const float4*)(WBb + o + 4); \
    Z##i = *(const float4*)(WBb + o + 8); \
    w0c##i = *(WCb + (qq) * 8 + zv); }

#define PINB(i) asm volatile("" : "+v"(X##i.x), "+v"(X##i.y), "+v"(X##i.z), "+v"(X##i.w), \
                          "+v"(Y##i.x), "+v"(Y##i.y), "+v"(Y##i.z), "+v"(Y##i.w), \
                          "+v"(Z##i.x), "+v"(Z##i.y), "+v"(Z##i.z), "+v"(Z##i.w), \
                          "+v"(w0c##i));

#define CLD(v) ((v) < qlo ? qlo : (v))
    LOADB(0, CLD(nq))     LOADB(1, CLD(nq - 1)) LOADB(2, CLD(nq - 2)) LOADB(3, CLD(nq - 3))
    LOADB(4, CLD(nq - 4)) LOADB(5, CLD(nq - 5)) LOADB(6, CLD(nq - 6)) LOADB(7, CLD(nq - 7))

    if (rem & 1) {
        const int r = dend - 1;
        int j1 = 2 * lane, j2 = 2 * lane + 1;
        int t1 = r - j1; t1 = t1 > Tt - 1 ? Tt - 1 : t1; if (t1 < 0) t1 = 0;
        int t2 = r - j2; t2 = t2 > Tt - 1 ? Tt - 1 : t2; if (t2 < 0) t2 = 0;
        float2 F1 = outv[((size_t)b * Tt + t1) * U1 + j1];
        float2 F2 = outv[((size_t)b * Tt + t2) * U1 + j2];
        int tg = r - 128; if (tg < 0) tg = 0;
        float2 G = outv[((size_t)b * Tt + tg) * U1 + 128];
        float n1x = rotD<MODE>(wx, lane);
        float nx = lae2(F1.x + wx, F1.y + wy);
        float ny = lae2(F2.x + wy, F2.y + ((lane == 63) ? w128 : n1x));
        w128 = G.x + w128;
        wx = nx; wy = ny;
    }
    if (rem >= 2) {
        const int mpair = 2 * nq + 1;
        const float* prow = PCKb + (size_t)mpair * PCKROW;
        float4 Qp  = *(const float4*)(prow + (lane << 3));
        float2 Rp  = *(const float2*)(prow + (lane << 3) + 4);
        int lp = lane + 1 > 63 ? 63 : lane + 1;
        float4 QpN = *(const float4*)(prow + (lp << 3));
        float2 RpN = *(const float2*)(prow + (lp << 3) + 4);
        float4 Op  = COLb[mpair + zv];
        float n1x = rotD<MODE>(wx, lane), n1y = rotD<MODE>(wy, lane);
        float nx = lae3(Qp.x + wx, Qp.w + wy,
                        (lane == 63) ? (Op.z + w128) : (RpN.x + n1x));
        float ny = lae3(Qp.y + wy,
                        (lane == 63) ? (Op.y + w128) : (QpN.z + n1x),
                        (lane == 63) ? SENT : (RpN.y + n1y));
        w128 = Op.x + w128;
        wx = nx; wy = ny;
    }

#define COMPB(i) { \
    float n1x = rotD<MODE>(wx, lane), n1y = rotD<MODE>(wy, lane); \
    float n2x = rotD<MODE>(n1x, lane), n2y = rotD<MODE>(n1y, lane); \
    float nx = lae6(wx + X##i.x, wy + X##i.y, n1x + X##i.z, n1y + X##i.w, \
                    n2x + Y##i.x, Z##i.z + w128); \
    float ny = lae6(wy + Y##i.y, n1x + Y##i.z, n1y + Y##i.w, n2x + Z##i.x, \
                    n2y + Z##i.y, Z##i.w + w128); \
    w128 = w0c##i + w128; \
    wx = nx; wy = ny; }

    int q = nq;
    for (; q - 7 >= qlo; q -= 8) {
        PINB(0) COMPB(0) LOADB(0, CLD(q - 8))
        PINB(1) COMPB(1) LOADB(1, CLD(q - 9))
        PINB(2) COMPB(2) LOADB(2, CLD(q - 10))
        PINB(3) COMPB(3) LOADB(3, CLD(q - 11))
        PINB(4) COMPB(4) LOADB(4, CLD(q - 12))
        PINB(5) COMPB(5) LOADB(5, CLD(q - 13))
        PINB(6) COMPB(6) LOADB(6, CLD(q - 14))
        PINB(7) COMPB(7) LOADB(7, CLD(q - 15))
    }
#define TAILB(i) if (q >= qlo) { PINB(i) COMPB(i) q--; }
    TAILB(0) TAILB(1) TAILB(2) TAILB(3) TAILB(4) TAILB(5) TAILB(6)

    float* Bst = ws + ST_OFF + (size_t)b * 260 + 130;
    ((float2*)Bst)[lane] = make_float2(wx, wy);
    if (lane == 0) Bst[128] = w128;
#undef LOADB
#undef PINB
#undef CLD
#undef COMPB
#undef TAILB
}

__global__ __launch_bounds__(64) void dp_kernel(
    const int* __restrict__ logit_lens, const int* __restrict__ y_lens,
    float* __restrict__ ws)
{
    const int b   = blockIdx.x >> 1;
    const int dir = blockIdx.x & 1;
    const int lane = threadIdx.x;
    const int Tb = logit_lens[b];
    const int Ub = y_lens[b];
    const bool h = (Ub == 128);
    int li = lane;
    int r0 = __builtin_amdgcn_update_dpp(li, li, 0x13C, 0xF, 0xF, true);
    int r1 = __builtin_amdgcn_update_dpp(li, li, 0x134, 0xF, 0xF, true);
    int wantU = (lane + 63) & 63, wantD = (lane + 1) & 63;
    int mode = 2;
    if (__all(r0 == wantU) && __all(r1 == wantD)) mode = 0;
    else if (__all(r1 == wantU) && __all(r0 == wantD)) mode = 1;

    if (dir == 0) {
        if (mode == 0)      { if (h) fw_body<0, true>(b, lane, Tb, Ub, ws); else fw_body<0, false>(b, lane, Tb, Ub, ws); }
        else if (mode == 1) { if (h) fw_body<1, true>(b, lane, Tb, Ub, ws); else fw_body<1, false>(b, lane, Tb, Ub, ws); }
        else                { if (h) fw_body<2, true>(b, lane, Tb, Ub, ws); else fw_body<2, false>(b, lane, Tb, Ub, ws); }
    } else {
        if (mode == 0)      bw_body<0>(b, lane, Tb, Ub, ws);
        else if (mode == 1) bw_body<1>(b, lane, Tb, Ub, ws);
        else                bw_body<2>(b, lane, Tb, Ub, ws);
    }
}

// Combine: ll = lae_u(alpha_mid[u] + beta_mid[u]); res = -(ll + final_blank)*ln2
__global__ __launch_bounds__(64) void combine_kernel(
    const int* __restrict__ logit_lens, const int* __restrict__ y_lens,
    float* __restrict__ ws)
{
    const int b = blockIdx.x;
    const int lane = threadIdx.x;
    const float* F = ws + ST_OFF + (size_t)b * 260;
    const float* Bs = F + 130;
    float2 v = ((const float2*)F)[lane];
    float2 w = ((const float2*)Bs)[lane];
    float r = lae2(v.x + w.x, v.y + w.y);
    #pragma unroll
    for (int off = 32; off; off >>= 1)
        r = lae2(r, __shfl_xor(r, off));
    r = lae2(r, F[128] + Bs[128]);
    const int Tb = logit_lens[b], Ub = y_lens[b];
    const float2* outv = (const float2*)(ws + OUT_OFF);
    float pbf = outv[((size_t)b * Tt + (Tb - 1)) * U1 + Ub].x;
    if (lane == 0)
        ws[RES_OFF + b] = -(r + pbf) * K_LN2;
}

__global__ void mean_kernel(const float* __restrict__ res, float* __restrict__ out)
{
    if (threadIdx.x == 0) {
        float s = 0.0f;
        #pragma unroll
        for (int i = 0; i < Bb; ++i) s += res[i];
        out[0] = s * (1.0f / Bb);
    }
}

extern "C" void kernel_launch(void* const* d_in, const int* in_sizes, int n_in,
                              void* d_out, int out_size, void* d_ws, size_t ws_size,
                              hipStream_t stream) {
    const float* logits     = (const float*)d_in[0];
    const int*   y          = (const int*)d_in[1];
    const int*   logit_lens = (const int*)d_in[2];
    const int*   y_lens     = (const int*)d_in[3];
    float* ws  = (float*)d_ws;
    float* out = (float*)d_out;

    dim3 lgrid(Tt, Bb);
    lse_kernel<<<lgrid, 256, 0, stream>>>(logits, y, logit_lens, y_lens, ws);
    compose_kernel<<<Bb * 160, 256, 0, stream>>>(logit_lens, y_lens, ws);
    dp_kernel<<<Bb * 2, 64, 0, stream>>>(logit_lens, y_lens, ws);
    combine_kernel<<<Bb, 64, 0, stream>>>(logit_lens, y_lens, ws);
    mean_kernel<<<1, 64, 0, stream>>>(ws + RES_OFF, out);
}

// Round 26
// 57.051 us; speedup vs baseline: 1.6635x; 1.0219x over previous
//
#include <hip/hip_runtime.h>

#define Bb 8
#define Tt 512
#define Uu 128
#define U1 129
#define Vv 128

#define OUT_OFF 0                          // float2 OUT[b][t][u] linear
#define CTROWS 321                         // pair rows m (only mpair used now)
#define PCKROW 512                         // floats per packed pair row (64 lanes x 8)
#define PCKBSZ ((size_t)CTROWS * PCKROW)
#define PCK_OFF ((size_t)Bb * Tt * U1 * 2)
#define CTCOL_OFF (PCK_OFF + (size_t)Bb * PCKBSZ)      // float4 {A,B,C,0}[b][m]
#define WROWF 768                          // 64 lanes x 12 floats
#define WROWS 161
#define WBSZ ((size_t)WROWS * WROWF)
#define W_OFF (CTCOL_OFF + (size_t)Bb * CTROWS * 4)    // forward k=4 records
#define WCOL_OFF (W_OFF + (size_t)Bb * WBSZ)           // 8 floats per (b,q): u=128 row
#define WB_OFF (WCOL_OFF + (size_t)Bb * WROWS * 8)     // backward (transposed) records
#define ST_OFF (WB_OFF + (size_t)Bb * WBSZ)            // per b: fw 130 floats, bw 130
#define RES_OFF (ST_OFF + (size_t)Bb * 260)

#define K_LN2    0.6931471805599453f
#define K_INVLN2 1.4426950408889634f
#define SENT (-1.0e30f)                    // finite sentinel; exp2(-big)=0, no inf/NaN

__device__ __forceinline__ float fexp2(float x) {
    float r; asm("v_exp_f32 %0, %1" : "=v"(r) : "v"(x)); return r;
}
__device__ __forceinline__ float flog2(float x) {
    float r; asm("v_log_f32 %0, %1" : "=v"(r) : "v"(x)); return r;
}
__device__ __forceinline__ float fmax3(float x, float y, float z) {
    float r; asm("v_max3_f32 %0, %1, %2, %3" : "=v"(r) : "v"(x), "v"(y), "v"(z));
    return r;
}
__device__ __forceinline__ float lae2(float x, float y) {
    float dd = x - y;
    float nad = __builtin_bit_cast(float, __builtin_bit_cast(int, dd) | 0x80000000);
    return fmaxf(x, y) + flog2(1.0f + fexp2(nad));
}
__device__ __forceinline__ float lae3(float x, float y, float z) {
    float m = fmax3(x, y, z);
    return m + flog2(fexp2(x - m) + fexp2(y - m) + fexp2(z - m));
}
__device__ __forceinline__ float lae5(float a, float b, float c, float d, float e) {
    float m = fmax3(a, b, c);
    m = fmax3(m, d, e);
    return m + flog2(fexp2(a - m) + fexp2(b - m) + fexp2(c - m)
                   + fexp2(d - m) + fexp2(e - m));
}
__device__ __forceinline__ float lae6(float a, float b, float c, float d, float e, float f) {
    float m = fmaxf(fmax3(a, b, c), fmax3(d, e, f));
    return m + flog2(fexp2(a - m) + fexp2(b - m) + fexp2(c - m)
                   + fexp2(d - m) + fexp2(e - m) + fexp2(f - m));
}

// Stage A: band-restricted streaming LSE (unchanged).
__global__ __launch_bounds__(256) void lse_kernel(
    const float* __restrict__ logits, const int* __restrict__ y,
    const int* __restrict__ logit_lens, const int* __restrict__ y_lens,
    float* __restrict__ ws)
{
    const int b = blockIdx.y;
    const int t = blockIdx.x;
    if (t >= logit_lens[b]) return;
    const int Ue = y_lens[b];

    float2* outv = (float2*)(ws + OUT_OFF);
    const int wid  = threadIdx.x >> 6;
    const int lane = threadIdx.x & 63;
    const int g    = lane >> 4;
    const int gl   = lane & 15;
    const unsigned rowbase = ((unsigned)b * Tt + t) * U1;
    const int yb = b * Uu;

    for (int u0 = wid * 8; u0 <= Ue; u0 += 32) {
        const int ua = u0 + g;
        const int ub = u0 + 4 + g;
        const int uca = ua > Ue ? Ue : ua;
        const int ucb = ub > Ue ? Ue : ub;
        const float* pa = logits + (size_t)(rowbase + uca) * Vv;
        const float* pb = logits + (size_t)(rowbase + ucb) * Vv;
        float4 a1 = *(const float4*)(pa + gl * 4);
        float4 a2 = *(const float4*)(pa + 64 + gl * 4);
        float4 b1 = *(const float4*)(pb + gl * 4);
        float4 b2 = *(const float4*)(pb + 64 + gl * 4);

        float sa = (fexp2(a1.x * K_INVLN2) + fexp2(a1.y * K_INVLN2))
                 + (fexp2(a1.z * K_INVLN2) + fexp2(a1.w * K_INVLN2))
                 + (fexp2(a2.x * K_INVLN2) + fexp2(a2.y * K_INVLN2))
                 + (fexp2(a2.z * K_INVLN2) + fexp2(a2.w * K_INVLN2));
        float sb = (fexp2(b1.x * K_INVLN2) + fexp2(b1.y * K_INVLN2))
                 + (fexp2(b1.z * K_INVLN2) + fexp2(b1.w * K_INVLN2))
                 + (fexp2(b2.x * K_INVLN2) + fexp2(b2.y * K_INVLN2))
                 + (fexp2(b2.z * K_INVLN2) + fexp2(b2.w * K_INVLN2));
        #pragma unroll
        for (int off = 8; off; off >>= 1) {
            sa += __shfl_xor(sa, off);
            sb += __shfl_xor(sb, off);
        }
        float lseA = flog2(sa);
        float lseB = flog2(sb);

        float emA = SENT, emB = SENT;
        if (uca < Uu) {
            int yv = y[yb + uca];
            int c = yv & 3;
            float4 cv = (yv & 64) ? a2 : a1;
            float cand = (c == 0) ? cv.x : (c == 1) ? cv.y : (c == 2) ? cv.z : cv.w;
            float ev = __shfl(cand, (lane & 48) | ((yv & 63) >> 2));
            emA = ev * K_INVLN2 - lseA;
        }
        if (ucb < Uu) {
            int yv = y[yb + ucb];
            int c = yv & 3;
            float4 cv = (yv & 64) ? b2 : b1;
            float cand = (c == 0) ? cv.x : (c == 1) ? cv.y : (c == 2) ? cv.z : cv.w;
            float ev = __shfl(cand, (lane & 48) | ((yv & 63) >> 2));
            emB = ev * K_INVLN2 - lseB;
        }
        if (gl == 0) {
            if (ua <= Ue) outv[rowbase + ua] = make_float2(a1.x * K_INVLN2 - lseA, emA);
            if (ub <= Ue) outv[rowbase + ub] = make_float2(b1.x * K_INVLN2 - lseB, emB);
        }
    }
}

// Stage B+C fused: compose pair matrices m1=2q-1, m2=2q directly from OUT.
// Emits forward W records + backward (transposed) records; q = nq+1 branch
// writes only the packed pair row mpair = 2nq+1 (+ CTCOL) for bw's pair-tail.
__global__ __launch_bounds__(256) void compose_kernel(
    const int* __restrict__ logit_lens, const int* __restrict__ y_lens,
    float* __restrict__ ws)
{
    const int b = blockIdx.x / 160;
    const int q = blockIdx.x - b * 160 + 1;        // 1..160
    const int dend = logit_lens[b] - 1 + y_lens[b];
    const int nq = dend >> 2;
    const bool full = (4 * q <= dend);
    const bool pair_only = (!full) && (q == nq + 1);
    if (!full && !pair_only) return;
    const float2* outv = (const float2*)(ws + OUT_OFF);

    __shared__ float2 D[4][U1];
    __shared__ float a1s[131], b1s[131], c1s[131];
    __shared__ float wrk[WROWF], wrkB[WROWF];
    __shared__ float sW0[129], sW1[129], sW2[129], sW3[129], sW4[129];
    __shared__ float pckS[PCKROW];
    const int u = threadIdx.x;

    for (int i = threadIdx.x; i < 4 * U1; i += 256) {
        int row = i / U1, j = i - row * U1;
        int r = 4 * (q - 1) + row;
        int t = r - j;
        D[row][j] = (t >= 0 && t < Tt) ? outv[((size_t)b * Tt + t) * U1 + j]
                                       : make_float2(SENT, SENT);
    }
    __syncthreads();

    float A2r = SENT, B2r = SENT, C2r = SENT;
    if (u < 2) { a1s[u] = SENT; b1s[u] = SENT; c1s[u] = SENT; }
    if (u <= 128) {
        float2 d1 = D[0][u], d2 = D[1][u];
        float2 d1m = (u >= 1) ? D[0][u - 1] : make_float2(SENT, SENT);
        float d2my  = (u >= 1) ? D[1][u - 1].y : SENT;
        float d1m2y = (u >= 2) ? D[0][u - 2].y : SENT;
        a1s[u + 2] = d1.x + d2.x;
        b1s[u + 2] = lae2(d1m.y + d2.x, d1m.x + d2my);
        c1s[u + 2] = d1m2y + d2my;
        float2 e1 = D[2][u], e2 = D[3][u];
        float2 e1m = (u >= 1) ? D[2][u - 1] : make_float2(SENT, SENT);
        float e2my  = (u >= 1) ? D[3][u - 1].y : SENT;
        float e1m2y = (u >= 2) ? D[2][u - 2].y : SENT;
        A2r = e1.x + e2.x;
        B2r = lae2(e1m.y + e2.x, e1m.x + e2my);
        C2r = e1m2y + e2my;
    }
    __syncthreads();

    if (pair_only) {
        if (u <= 128) {
            float A = a1s[u + 2], B = b1s[u + 2], C = c1s[u + 2];
            if (u < 128) {
                int base = (u >> 1) * 8 + (u & 1);
                pckS[base]     = A;
                pckS[base + 2] = B;
                pckS[base + 4] = C;
                if ((u & 1) == 0) { pckS[base + 6] = 0.0f; pckS[base + 7] = 0.0f; }
            } else {
                ((float4*)(ws + CTCOL_OFF))[(size_t)b * CTROWS + (2 * q - 1)]
                    = make_float4(A, B, C, 0.0f);
            }
        }
        __syncthreads();
        float* pckG = ws + PCK_OFF + (size_t)b * PCKBSZ + (size_t)(2 * q - 1) * PCKROW;
        for (int i = threadIdx.x; i < PCKROW; i += 256) pckG[i] = pckS[i];
        return;
    }

    if (u <= 128) {
        float A1 = a1s[u + 2], A1m = a1s[u + 1], A1m2 = a1s[u];
        float B1 = b1s[u + 2], B1m = b1s[u + 1], B1m2 = b1s[u];
        float C1 = c1s[u + 2], C1m = c1s[u + 1], C1m2 = c1s[u];
        float W0 = A2r + A1;
        float W1 = lae2(A2r + B1, B2r + A1m);
        float W2 = lae3(A2r + C1, B2r + B1m, C2r + A1m2);
        float W3 = lae2(B2r + C1m, C2r + B1m2);
        float W4 = C2r + C1m2;
        sW0[u] = W0; sW1[u] = W1; sW2[u] = W2; sW3[u] = W3; sW4[u] = W4;
        if (u < 128) {
            int base = (u >> 1) * 12 + (u & 1);
            wrk[base]     = W0;
            wrk[base + 2] = W1;
            wrk[base + 4] = W2;
            wrk[base + 6] = W3;
            wrk[base + 8] = W4;
            if ((u & 1) == 0) { wrk[base + 10] = 0.0f; wrk[base + 11] = 0.0f; }
        } else {
            float* wc = ws + WCOL_OFF + ((size_t)b * WROWS + q) * 8;
            wc[0] = W0; wc[1] = W1; wc[2] = W2; wc[3] = W3; wc[4] = W4;
            wc[5] = 0.0f; wc[6] = 0.0f; wc[7] = 0.0f;
        }
    }
    __syncthreads();

    if (u < 64) {
        const int l = u, e = 2 * l;
        float cx2 = (e + 2 <= 127) ? sW2[e + 2] : SENT;
        float cx3 = (e + 3 <= 127) ? sW3[e + 3] : SENT;
        float cx4 = (e + 4 <= 127) ? sW4[e + 4] : SENT;
        float cy1 = (e + 2 <= 127) ? sW1[e + 2] : SENT;
        float cy2 = (e + 3 <= 127) ? sW2[e + 3] : SENT;
        float cy3 = (e + 4 <= 127) ? sW3[e + 4] : SENT;
        float cy4 = (e + 5 <= 127) ? sW4[e + 5] : SENT;
        float c5x = (l == 62) ? sW4[128] : (l == 63) ? sW2[128] : SENT;
        float c5y = (l == 62) ? sW3[128] : (l == 63) ? sW1[128] : SENT;
        float* rb = wrkB + l * 12;
        rb[0] = sW0[e];     rb[1] = sW1[e + 1]; rb[2]  = cx2; rb[3]  = cx3;
        rb[4] = cx4;        rb[5] = sW0[e + 1]; rb[6]  = cy1; rb[7]  = cy2;
        rb[8] = cy3;        rb[9] = cy4;        rb[10] = c5x; rb[11] = c5y;
    }
    __syncthreads();

    float* wg  = ws + W_OFF  + (size_t)b * WBSZ + (size_t)q * WROWF;
    float* wbg = ws + WB_OFF + (size_t)b * WBSZ + (size_t)q * WROWF;
    for (int i = threadIdx.x; i < WROWF; i += 256) { wg[i] = wrk[i]; wbg[i] = wrkB[i]; }
}

// rotate up: lane i <- lane i-1. MODE 0/1: DPP (runtime-verified), 2: shuffle.
template<int MODE>
__device__ __forceinline__ float rotU(float x, int lane) {
    if constexpr (MODE == 2) {
        return __shfl(x, (lane + 63) & 63);
    } else {
        constexpr int CTRL = (MODE == 0) ? 0x13C : 0x134;
        int i = __builtin_bit_cast(int, x);
        i = __builtin_amdgcn_update_dpp(i, i, CTRL, 0xF, 0xF, true);
        return __builtin_bit_cast(float, i);
    }
}
// rotate down: lane i <- lane i+1.
template<int MODE>
__device__ __forceinline__ float rotD(float x, int lane) {
    if constexpr (MODE == 2) {
        return __shfl(x, (lane + 1) & 63);
    } else {
        constexpr int CTRL = (MODE == 0) ? 0x134 : 0x13C;
        int i = __builtin_bit_cast(int, x);
        i = __builtin_amdgcn_update_dpp(i, i, CTRL, 0xF, 0xF, true);
        return __builtin_bit_cast(float, i);
    }
}

// FORWARD half: q = 1..qmid, store alpha state. qmid = 8nq/15 (bw heavier).
template<int MODE, bool H128>
__device__ __forceinline__ void fw_body(int b, int lane, int Tb, int Ub,
                                        float* __restrict__ ws)
{
    const float* WTb = ws + W_OFF + (size_t)b * WBSZ;
    const float* WCb = ws + WCOL_OFF + (size_t)b * WROWS * 8;
    int zv; asm volatile("v_mov_b32 %0, 0" : "=v"(zv));

    float px = (lane == 0) ? 0.0f : SENT;
    float py = SENT, p2 = SENT;
    const int dend = Tb - 1 + Ub;
    const int nq   = dend >> 2;
    const int qend = (nq * 8) / 15;    // qmid

    float4 A0,A1,A2,A3,A4,A5,A6,A7;
    float4 B0,B1,B2,B3,B4,B5,B6,B7;
    float2 C0,C1,C2,C3,C4,C5,C6,C7;
    float4 Oa0,Oa1,Oa2,Oa3,Oa4,Oa5,Oa6,Oa7;
    float2 Oc0,Oc1,Oc2,Oc3,Oc4,Oc5,Oc6,Oc7;

#define LOADW(i, qq) { unsigned o = (unsigned)(qq) * WROWF + lane * 12; \
    A##i = *(const float4*)(WTb + o); \
    B##i = *(const float4*)(WTb + o + 4); \
    C##i = *(const float2*)(WTb + o + 8); \
    if constexpr (H128) { \
        Oa##i = *(const float4*)(WCb + (qq) * 8 + zv); \
        Oc##i = *(const float2*)(WCb + (qq) * 8 + 4 + zv); } }

#define PIN(i) if constexpr (H128) { \
        asm volatile("" : "+v"(A##i.x), "+v"(A##i.y), "+v"(A##i.z), "+v"(A##i.w), \
                          "+v"(B##i.x), "+v"(B##i.y), "+v"(B##i.z), "+v"(B##i.w), \
                          "+v"(C##i.x), "+v"(C##i.y), \
                          "+v"(Oa##i.x), "+v"(Oa##i.y), "+v"(Oa##i.z), "+v"(Oa##i.w), \
                          "+v"(Oc##i.x)); \
    } else { \
        asm volatile("" : "+v"(A##i.x), "+v"(A##i.y), "+v"(A##i.z), "+v"(A##i.w), \
                          "+v"(B##i.x), "+v"(B##i.y), "+v"(B##i.z), "+v"(B##i.w), \
                          "+v"(C##i.x), "+v"(C##i.y)); \
    }

#define COMP4(i) { \
    float p1y = rotU<MODE>(py, lane); \
    float p1x = rotU<MODE>(px, lane); \
    float p2y = rotU<MODE>(p1y, lane); \
    float p2x = rotU<MODE>(p1x, lane); \
    float nx = lae5(px + A##i.x, p1y + A##i.z, p1x + B##i.x, p2y + B##i.z, p2x + C##i.x); \
    float ny = lae5(py + A##i.y, px + A##i.w, p1y + B##i.y, p1x + B##i.w, p2y + C##i.y); \
    if constexpr (H128) p2 = lae5(p2 + Oa##i.x, p1y + Oa##i.y, p1x + Oa##i.z, \
                                  p2y + Oa##i.w, p2x + Oc##i.x); \
    px = nx; py = ny; }

    LOADW(0,1) LOADW(1,2) LOADW(2,3) LOADW(3,4)
    LOADW(4,5) LOADW(5,6) LOADW(6,7) LOADW(7,8)

    int q = 1;
    for (; q + 7 <= qend; q += 8) {
        PIN(0) COMP4(0) { int dn = q + 8  > qend ? qend : q + 8;  LOADW(0, dn) }
        PIN(1) COMP4(1) { int dn = q + 9  > qend ? qend : q + 9;  LOADW(1, dn) }
        PIN(2) COMP4(2) { int dn = q + 10 > qend ? qend : q + 10; LOADW(2, dn) }
        PIN(3) COMP4(3) { int dn = q + 11 > qend ? qend : q + 11; LOADW(3, dn) }
        PIN(4) COMP4(4) { int dn = q + 12 > qend ? qend : q + 12; LOADW(4, dn) }
        PIN(5) COMP4(5) { int dn = q + 13 > qend ? qend : q + 13; LOADW(5, dn) }
        PIN(6) COMP4(6) { int dn = q + 14 > qend ? qend : q + 14; LOADW(6, dn) }
        PIN(7) COMP4(7) { int dn = q + 15 > qend ? qend : q + 15; LOADW(7, dn) }
    }
#define TAILW(i) if (q <= qend) { PIN(i) COMP4(i) q++; }
    TAILW(0) TAILW(1) TAILW(2) TAILW(3) TAILW(4) TAILW(5) TAILW(6)

    float* F = ws + ST_OFF + (size_t)b * 260;
    ((float2*)F)[lane] = make_float2(px, py);
    if (lane == 0) F[128] = H128 ? p2 : SENT;
#undef LOADW
#undef PIN
#undef COMP4
#undef TAILW
}

// BACKWARD half: tails^T, then P_q^T for q = nq..qmid+1; store beta state.
template<int MODE>
__device__ __forceinline__ void bw_body(int b, int lane, int Tb, int Ub,
                                        float* __restrict__ ws)
{
    const float2* outv = (const float2*)(ws + OUT_OFF);
    const float* PCKb = ws + PCK_OFF + (size_t)b * PCKBSZ;
    const float4* COLb = (const float4*)(ws + CTCOL_OFF) + (size_t)b * CTROWS;
    const float* WBb = ws + WB_OFF + (size_t)b * WBSZ;
    const float* WCb = ws + WCOL_OFF + (size_t)b * WROWS * 8;
    int zv; asm volatile("v_mov_b32 %0, 0" : "=v"(zv));

    const int dend = Tb - 1 + Ub;
    const int nq   = dend >> 2;
    const int qlo  = (nq * 8) / 15 + 1;    // qmid + 1
    const int rem  = dend & 3;

    float wx = SENT, wy = SENT, w128 = SENT;
    if (Ub == 128) w128 = 0.0f;
    else if (lane == (Ub >> 1)) { if (Ub & 1) wy = 0.0f; else wx = 0.0f; }

    float4 X0,X1,X2,X3,X4,X5,X6,X7;
    float4 Y0,Y1,Y2,Y3,Y4,Y5,Y6,Y7;
    float4 Z0,Z1,Z2,Z3,Z4,Z5,Z6,Z7;
    float w0c0,w0c1,w0c2,w0c3,w0c4,w0c5,w0c6,w0c7;

#define LOADB(i, qq) { unsigned o = (unsigned)(qq) * WROWF + lane * 12; \
    X##i = *(const float4*)(WBb + o); \
    Y##i = *(const float4*)(WBb + o + 4); \
    Z##i = *(const float4*)(WBb + o + 8); \
    w0c##i = *(WCb + (qq) * 8 + zv); }

#define PINB(i) asm volatile("" : "+v"(X##i.x), "+v"(X##i.y), "+v"(X##i.z), "+v"(X##i.w), \
                          "+v"(Y##i.x), "+v"(Y##i.y), "+v"(Y##i.z), "+v"(Y##i.w), \
                          "+v"(Z##i.x), "+v"(Z##i.y), "+v"(Z##i.z), "+v"(Z##i.w), \
                          "+v"(w0c##i));

#define CLD(v) ((v) < qlo ? qlo : (v))
    LOADB(0, CLD(nq))     LOADB(1, CLD(nq - 1)) LOADB(2, CLD(nq - 2)) LOADB(3, CLD(nq - 3))
    LOADB(4, CLD(nq - 4)) LOADB(5, CLD(nq - 5)) LOADB(6, CLD(nq - 6)) LOADB(7, CLD(nq - 7))

    if (rem & 1) {
        const int r = dend - 1;
        int j1 = 2 * lane, j2 = 2 * lane + 1;
        int t1 = r - j1; t1 = t1 > Tt - 1 ? Tt - 1 : t1; if (t1 < 0) t1 = 0;
        int t2 = r - j2; t2 = t2 > Tt - 1 ? Tt - 1 : t2; if (t2 < 0) t2 = 0;
        float2 F1 = outv[((size_t)b * Tt + t1) * U1 + j1];
        float2 F2 = outv[((size_t)b * Tt + t2) * U1 + j2];
        int tg = r - 128; if (tg < 0) tg = 0;
        float2 G = outv[((size_t)b * Tt + tg) * U1 + 128];
        float n1x = rotD<MODE>(wx, lane);
        float nx = lae2(F1.x + wx, F1.y + wy);
        float ny = lae2(F2.x + wy, F2.y + ((lane == 63) ? w128 : n1x));
        w128 = G.x + w128;
        wx = nx; wy = ny;
    }
    if (rem >= 2) {
        const int mpair = 2 * nq + 1;
        const float* prow = PCKb + (size_t)mpair * PCKROW;
        float4 Qp  = *(const float4*)(prow + (lane << 3));
        float2 Rp  = *(const float2*)(prow + (lane << 3) + 4);
        int lp = lane + 1 > 63 ? 63 : lane + 1;
        float4 QpN = *(const float4*)(prow + (lp << 3));
        float2 RpN = *(const float2*)(prow + (lp << 3) + 4);
        float4 Op  = COLb[mpair + zv];
        float n1x = rotD<MODE>(wx, lane), n1y = rotD<MODE>(wy, lane);
        float nx = lae3(Qp.x + wx, Qp.w + wy,
                        (lane == 63) ? (Op.z + w128) : (RpN.x + n1x));
        float ny = lae3(Qp.y + wy,
                        (lane == 63) ? (Op.y + w128) : (QpN.z + n1x),
                        (lane == 63) ? SENT : (RpN.y + n1y));
        w128 = Op.x + w128;
        wx = nx; wy = ny;
    }

#define COMPB(i) { \
    float n1x = rotD<MODE>(wx, lane), n1y = rotD<MODE>(wy, lane); \
    float n2x = rotD<MODE>(n1x, lane), n2y = rotD<MODE>(n1y, lane); \
    float nx = lae6(wx + X##i.x, wy + X##i.y, n1x + X##i.z, n1y + X##i.w, \
                    n2x + Y##i.x, Z##i.z + w128); \
    float ny = lae6(wy + Y##i.y, n1x + Y##i.z, n1y + Y##i.w, n2x + Z##i.x, \
                    n2y + Z##i.y, Z##i.w + w128); \
    w128 = w0c##i + w128; \
    wx = nx; wy = ny; }

    int q = nq;
    for (; q - 7 >= qlo; q -= 8) {
        PINB(0) COMPB(0) LOADB(0, CLD(q - 8))
        PINB(1) COMPB(1) LOADB(1, CLD(q - 9))
        PINB(2) COMPB(2) LOADB(2, CLD(q - 10))
        PINB(3) COMPB(3) LOADB(3, CLD(q - 11))
        PINB(4) COMPB(4) LOADB(4, CLD(q - 12))
        PINB(5) COMPB(5) LOADB(5, CLD(q - 13))
        PINB(6) COMPB(6) LOADB(6, CLD(q - 14))
        PINB(7) COMPB(7) LOADB(7, CLD(q - 15))
    }
#define TAILB(i) if (q >= qlo) { PINB(i) COMPB(i) q--; }
    TAILB(0) TAILB(1) TAILB(2) TAILB(3) TAILB(4) TAILB(5) TAILB(6)

    float* Bst = ws + ST_OFF + (size_t)b * 260 + 130;
    ((float2*)Bst)[lane] = make_float2(wx, wy);
    if (lane == 0) Bst[128] = w128;
#undef LOADB
#undef PINB
#undef CLD
#undef COMPB
#undef TAILB
}

__global__ __launch_bounds__(64) void dp_kernel(
    const int* __restrict__ logit_lens, const int* __restrict__ y_lens,
    float* __restrict__ ws)
{
    const int b   = blockIdx.x >> 1;
    const int dir = blockIdx.x & 1;
    const int lane = threadIdx.x;
    const int Tb = logit_lens[b];
    const int Ub = y_lens[b];
    const bool h = (Ub == 128);
    int li = lane;
    int r0 = __builtin_amdgcn_update_dpp(li, li, 0x13C, 0xF, 0xF, true);
    int r1 = __builtin_amdgcn_update_dpp(li, li, 0x134, 0xF, 0xF, true);
    int wantU = (lane + 63) & 63, wantD = (lane + 1) & 63;
    int mode = 2;
    if (__all(r0 == wantU) && __all(r1 == wantD)) mode = 0;
    else if (__all(r1 == wantU) && __all(r0 == wantD)) mode = 1;

    if (dir == 0) {
        if (mode == 0)      { if (h) fw_body<0, true>(b, lane, Tb, Ub, ws); else fw_body<0, false>(b, lane, Tb, Ub, ws); }
        else if (mode == 1) { if (h) fw_body<1, true>(b, lane, Tb, Ub, ws); else fw_body<1, false>(b, lane, Tb, Ub, ws); }
        else                { if (h) fw_body<2, true>(b, lane, Tb, Ub, ws); else fw_body<2, false>(b, lane, Tb, Ub, ws); }
    } else {
        if (mode == 0)      bw_body<0>(b, lane, Tb, Ub, ws);
        else if (mode == 1) bw_body<1>(b, lane, Tb, Ub, ws);
        else                bw_body<2>(b, lane, Tb, Ub, ws);
    }
}

// Finish (combine + mean fused): wave b reduces ll_b = lae_u(alpha+beta) + blank;
// then thread 0 averages the 8 losses. One launch instead of two.
__global__ __launch_bounds__(512) void finish_kernel(
    const int* __restrict__ logit_lens, const int* __restrict__ y_lens,
    float* __restrict__ ws, float* __restrict__ out)
{
    const int b = threadIdx.x >> 6;
    const int lane = threadIdx.x & 63;
    const float* F = ws + ST_OFF + (size_t)b * 260;
    const float* Bs = F + 130;
    float2 v = ((const float2*)F)[lane];
    float2 w = ((const float2*)Bs)[lane];
    float r = lae2(v.x + w.x, v.y + w.y);
    #pragma unroll
    for (int off = 32; off; off >>= 1)
        r = lae2(r, __shfl_xor(r, off));
    r = lae2(r, F[128] + Bs[128]);
    const int Tb = logit_lens[b], Ub = y_lens[b];
    const float2* outv = (const float2*)(ws + OUT_OFF);
    float pbf = outv[((size_t)b * Tt + (Tb - 1)) * U1 + Ub].x;

    __shared__ float res[Bb];
    if (lane == 0) res[b] = -(r + pbf) * K_LN2;
    __syncthreads();
    if (threadIdx.x == 0) {
        float s = 0.0f;
        #pragma unroll
        for (int i = 0; i < Bb; ++i) s += res[i];
        out[0] = s * (1.0f / Bb);
    }
}

extern "C" void kernel_launch(void* const* d_in, const int* in_sizes, int n_in,
                              void* d_out, int out_size, void* d_ws, size_t ws_size,
                              hipStream_t stream) {
    const float* logits     = (const float*)d_in[0];
    const int*   y          = (const int*)d_in[1];
    const int*   logit_lens = (const int*)d_in[2];
    const int*   y_lens     = (const int*)d_in[3];
    float* ws  = (float*)d_ws;
    float* out = (float*)d_out;

    dim3 lgrid(Tt, Bb);
    lse_kernel<<<lgrid, 256, 0, stream>>>(logits, y, logit_lens, y_lens, ws);
    compose_kernel<<<Bb * 160, 256, 0, stream>>>(logit_lens, y_lens, ws);
    dp_kernel<<<Bb * 2, 64, 0, stream>>>(logit_lens, y_lens, ws);
    finish_kernel<<<1, 512, 0, stream>>>(logit_lens, y_lens, ws, out);
}